// Round 1
// baseline (1397.246 us; speedup 1.0000x reference)
//
#include <hip/hip_runtime.h>
#include <hip/hip_bf16.h>

#define N_FEATS 128

// ---------------------------------------------------------------------------
// Kernel 1: transpose W [128][128] -> Wt [128][128] (Wt[i][o] = W[o][i])
// One-shot, 64 KB, cost negligible.
// ---------------------------------------------------------------------------
__global__ void gcn_transpose_w(const float* __restrict__ W, float* __restrict__ Wt) {
    int t = blockIdx.x * blockDim.x + threadIdx.x;   // 0 .. 16383
    int o = t >> 7;
    int i = t & 127;
    Wt[i * N_FEATS + o] = W[o * N_FEATS + i];
}

// ---------------------------------------------------------------------------
// Kernel 2: scatter-add  agg[dst[e]] += feature[src[e]]
// 32 threads per edge, each thread owns a float4 (16 B) slice of the row.
// agg == d_out (zeroed first). Bounds-guarded so a wrong index-dtype
// assumption shows up as an accuracy failure, not a fault.
// ---------------------------------------------------------------------------
__global__ void gcn_scatter_add(const float* __restrict__ feat,
                                const int* __restrict__ src,
                                const int* __restrict__ dst,
                                float* __restrict__ agg,
                                int n_edges, int n_nodes) {
    long long tid = (long long)blockIdx.x * blockDim.x + threadIdx.x;
    int e = (int)(tid >> 5);
    if (e >= n_edges) return;
    int j = (int)(tid & 31);

    int s = src[e];
    int d = dst[e];
    if ((unsigned)s >= (unsigned)n_nodes || (unsigned)d >= (unsigned)n_nodes) return;

    const float4 v = *reinterpret_cast<const float4*>(feat + (size_t)s * N_FEATS + j * 4);
    float* p = agg + (size_t)d * N_FEATS + j * 4;
    atomicAdd(p + 0, v.x);
    atomicAdd(p + 1, v.y);
    atomicAdd(p + 2, v.z);
    atomicAdd(p + 3, v.w);
}

// ---------------------------------------------------------------------------
// Kernel 3: in-place GEMM  out[n][o] = sum_i agg[n][i] * Wt[i][o] + b[o]
// Block = 256 threads, 32 node-rows per block. Rows staged to LDS, then
// overwritten — safe because each block only touches its own rows.
// Thread tile: 4 nodes x 4 outputs (float4 on the output dim).
// ---------------------------------------------------------------------------
__launch_bounds__(256)
__global__ void gcn_gemm_inplace(float* __restrict__ out,
                                 const float* __restrict__ Wt,
                                 const float* __restrict__ b,
                                 int n_nodes) {
    __shared__ float a_lds[32 * N_FEATS];   // 16 KB

    const int t = threadIdx.x;
    const int node0 = blockIdx.x * 32;
    const int rows = min(32, n_nodes - node0);

    // stage A tile (float4-coalesced)
    float4* a4 = reinterpret_cast<float4*>(a_lds);
    const float4* out4 = reinterpret_cast<const float4*>(out + (size_t)node0 * N_FEATS);
    const int nflt4 = rows * (N_FEATS / 4);
    for (int idx = t; idx < nflt4; idx += 256) a4[idx] = out4[idx];
    __syncthreads();

    const int oq = t & 31;    // output float4 index: outputs oq*4 .. oq*4+3
    const int ng = t >> 5;    // node group 0..7 -> nodes ng*4 .. ng*4+3

    const float4 bb = reinterpret_cast<const float4*>(b)[oq];
    float4 acc[4];
#pragma unroll
    for (int k = 0; k < 4; ++k) acc[k] = bb;

    const float4* Wt4 = reinterpret_cast<const float4*>(Wt);
#pragma unroll 4
    for (int i = 0; i < N_FEATS; ++i) {
        const float4 w = Wt4[i * 32 + oq];
#pragma unroll
        for (int k = 0; k < 4; ++k) {
            const float a = a_lds[(ng * 4 + k) * N_FEATS + i];
            acc[k].x += a * w.x;
            acc[k].y += a * w.y;
            acc[k].z += a * w.z;
            acc[k].w += a * w.w;
        }
    }

    __syncthreads();   // all LDS reads done before rows are overwritten

#pragma unroll
    for (int k = 0; k < 4; ++k) {
        const int r = ng * 4 + k;
        if (r < rows) {
            reinterpret_cast<float4*>(out + (size_t)(node0 + r) * N_FEATS)[oq] = acc[k];
        }
    }
}

extern "C" void kernel_launch(void* const* d_in, const int* in_sizes, int n_in,
                              void* d_out, int out_size, void* d_ws, size_t ws_size,
                              hipStream_t stream) {
    const float* feature = (const float*)d_in[0];
    const int*   src     = (const int*)d_in[1];
    const int*   dst     = (const int*)d_in[2];
    const float* W       = (const float*)d_in[3];
    const float* b       = (const float*)d_in[4];
    float* out = (float*)d_out;

    const int n_nodes = in_sizes[0] / N_FEATS;
    const int n_edges = in_sizes[1];

    float* Wt = (float*)d_ws;   // 64 KB scratch

    // 1. zero the aggregation buffer (= d_out)
    hipMemsetAsync(d_out, 0, (size_t)n_nodes * N_FEATS * sizeof(float), stream);

    // 2. transpose W
    gcn_transpose_w<<<(N_FEATS * N_FEATS) / 256, 256, 0, stream>>>(W, Wt);

    // 3. scatter-add edges
    {
        long long total = (long long)n_edges * 32;
        int blocks = (int)((total + 255) / 256);
        gcn_scatter_add<<<blocks, 256, 0, stream>>>(feature, src, dst, out, n_edges, n_nodes);
    }

    // 4. in-place linear
    {
        int blocks = (n_nodes + 31) / 32;
        gcn_gemm_inplace<<<blocks, 256, 0, stream>>>(out, Wt, b, n_nodes);
    }
}

// Round 5
// 298.337 us; speedup vs baseline: 4.6835x; 4.6835x over previous
//
#include <hip/hip_runtime.h>
#include <hip/hip_bf16.h>

#define N_FEATS 128

// ---------------------------------------------------------------------------
// Kernel: transpose W [128][128] -> Wt [128][128] (Wt[i][o] = W[o][i])
// ---------------------------------------------------------------------------
__global__ void gcn_transpose_w(const float* __restrict__ W, float* __restrict__ Wt) {
    int t = blockIdx.x * blockDim.x + threadIdx.x;   // 0 .. 16383
    int o = t >> 7;
    int i = t & 127;
    Wt[i * N_FEATS + o] = W[o * N_FEATS + i];
}

// ---------------------------------------------------------------------------
// CSR build step 1: degree histogram of dst
// ---------------------------------------------------------------------------
__global__ void gcn_hist(const int* __restrict__ dst, int* __restrict__ deg,
                         int n_edges, int n_nodes) {
    int e = blockIdx.x * blockDim.x + threadIdx.x;
    if (e >= n_edges) return;
    int d = dst[e];
    if ((unsigned)d < (unsigned)n_nodes) atomicAdd(&deg[d], 1);
}

// ---------------------------------------------------------------------------
// CSR build step 2: exclusive scan deg -> row_start (single block, 1024 thr).
// Also writes row_start[n] = total.
// ---------------------------------------------------------------------------
__launch_bounds__(1024)
__global__ void gcn_scan(const int* __restrict__ deg, int* __restrict__ row_start, int n) {
    __shared__ int lds[1024];
    __shared__ int s_running;
    const int t = threadIdx.x;
    if (t == 0) s_running = 0;
    __syncthreads();
    for (int base = 0; base < n; base += 1024) {
        int x = (base + t < n) ? deg[base + t] : 0;
        lds[t] = x;
        __syncthreads();
        for (int off = 1; off < 1024; off <<= 1) {
            int v = (t >= off) ? lds[t - off] : 0;
            __syncthreads();
            lds[t] += v;
            __syncthreads();
        }
        int incl = lds[t];
        int running = s_running;
        if (base + t < n) row_start[base + t] = running + incl - x;
        __syncthreads();
        if (t == 1023) s_running = running + lds[1023];
        __syncthreads();
    }
    if (t == 0) row_start[n] = s_running;
}

// ---------------------------------------------------------------------------
// CSR build step 3: scatter src ids into per-dst slots
// ---------------------------------------------------------------------------
__global__ void gcn_build_csr(const int* __restrict__ src, const int* __restrict__ dst,
                              const int* __restrict__ row_start, int* __restrict__ cursor,
                              int* __restrict__ csr_src, int n_edges, int n_nodes) {
    int e = blockIdx.x * blockDim.x + threadIdx.x;
    if (e >= n_edges) return;
    int d = dst[e];
    int s = src[e];
    if ((unsigned)d >= (unsigned)n_nodes || (unsigned)s >= (unsigned)n_nodes) return;
    int pos = atomicAdd(&cursor[d], 1);
    csr_src[row_start[d] + pos] = s;
}

// ---------------------------------------------------------------------------
// Aggregation (pull): one wave per node, lane owns a float2 column slice.
// out[node] = sum over csr_src rows of feature. No atomics.
// ---------------------------------------------------------------------------
__launch_bounds__(256)
__global__ void gcn_aggregate(const float* __restrict__ feat,
                              const int* __restrict__ row_start,
                              const int* __restrict__ csr_src,
                              float* __restrict__ out, int n_nodes) {
    int node = blockIdx.x * 4 + (threadIdx.x >> 6);
    if (node >= n_nodes) return;
    int lane = threadIdx.x & 63;
    int beg = row_start[node];
    int end = row_start[node + 1];
    const float2* f2 = reinterpret_cast<const float2*>(feat);
    float2 acc = make_float2(0.f, 0.f);
    for (int i = beg; i < end; ++i) {
        int s = csr_src[i];                       // wave-uniform load
        float2 v = f2[(size_t)s * 64 + lane];     // 512 B / wave, coalesced
        acc.x += v.x;
        acc.y += v.y;
    }
    reinterpret_cast<float2*>(out)[(size_t)node * 64 + lane] = acc;
}

// ---------------------------------------------------------------------------
// Fallback scatter-add (round-0 path) if ws_size is too small for CSR.
// ---------------------------------------------------------------------------
__global__ void gcn_scatter_add(const float* __restrict__ feat,
                                const int* __restrict__ src,
                                const int* __restrict__ dst,
                                float* __restrict__ agg,
                                int n_edges, int n_nodes) {
    long long tid = (long long)blockIdx.x * blockDim.x + threadIdx.x;
    int e = (int)(tid >> 5);
    if (e >= n_edges) return;
    int j = (int)(tid & 31);
    int s = src[e];
    int d = dst[e];
    if ((unsigned)s >= (unsigned)n_nodes || (unsigned)d >= (unsigned)n_nodes) return;
    const float4 v = *reinterpret_cast<const float4*>(feat + (size_t)s * N_FEATS + j * 4);
    float* p = agg + (size_t)d * N_FEATS + j * 4;
    atomicAdd(p + 0, v.x);
    atomicAdd(p + 1, v.y);
    atomicAdd(p + 2, v.z);
    atomicAdd(p + 3, v.w);
}

// ---------------------------------------------------------------------------
// In-place GEMM  out[n][o] = sum_i out[n][i] * Wt[i][o] + b[o]
// Block = 256 threads, 32 node-rows per block; rows staged to LDS first.
// ---------------------------------------------------------------------------
__launch_bounds__(256)
__global__ void gcn_gemm_inplace(float* __restrict__ out,
                                 const float* __restrict__ Wt,
                                 const float* __restrict__ b,
                                 int n_nodes) {
    __shared__ float a_lds[32 * N_FEATS];   // 16 KB

    const int t = threadIdx.x;
    const int node0 = blockIdx.x * 32;
    const int rows = min(32, n_nodes - node0);

    float4* a4 = reinterpret_cast<float4*>(a_lds);
    const float4* out4 = reinterpret_cast<const float4*>(out + (size_t)node0 * N_FEATS);
    const int nflt4 = rows * (N_FEATS / 4);
    for (int idx = t; idx < nflt4; idx += 256) a4[idx] = out4[idx];
    __syncthreads();

    const int oq = t & 31;    // output float4 index
    const int ng = t >> 5;    // node group 0..7

    const float4 bb = reinterpret_cast<const float4*>(b)[oq];
    float4 acc[4];
#pragma unroll
    for (int k = 0; k < 4; ++k) acc[k] = bb;

    const float4* Wt4 = reinterpret_cast<const float4*>(Wt);
#pragma unroll 4
    for (int i = 0; i < N_FEATS; ++i) {
        const float4 w = Wt4[i * 32 + oq];
#pragma unroll
        for (int k = 0; k < 4; ++k) {
            const float a = a_lds[(ng * 4 + k) * N_FEATS + i];
            acc[k].x += a * w.x;
            acc[k].y += a * w.y;
            acc[k].z += a * w.z;
            acc[k].w += a * w.w;
        }
    }

    __syncthreads();

#pragma unroll
    for (int k = 0; k < 4; ++k) {
        const int r = ng * 4 + k;
        if (r < rows) {
            reinterpret_cast<float4*>(out + (size_t)(node0 + r) * N_FEATS)[oq] = acc[k];
        }
    }
}

extern "C" void kernel_launch(void* const* d_in, const int* in_sizes, int n_in,
                              void* d_out, int out_size, void* d_ws, size_t ws_size,
                              hipStream_t stream) {
    const float* feature = (const float*)d_in[0];
    const int*   src     = (const int*)d_in[1];
    const int*   dst     = (const int*)d_in[2];
    const float* W       = (const float*)d_in[3];
    const float* b       = (const float*)d_in[4];
    float* out = (float*)d_out;

    const int n_nodes = in_sizes[0] / N_FEATS;
    const int n_edges = in_sizes[1];

    // ---- workspace layout (256 B aligned) ----
    char* ws = (char*)d_ws;
    size_t off = 0;
    auto take = [&](size_t bytes) -> char* {
        char* p = ws + off;
        off = (off + bytes + 255) & ~(size_t)255;
        return p;
    };
    float* Wt        = (float*)take((size_t)N_FEATS * N_FEATS * sizeof(float));
    int*   deg       = (int*)  take((size_t)n_nodes * sizeof(int));
    int*   row_start = (int*)  take(((size_t)n_nodes + 1) * sizeof(int));
    int*   cursor    = (int*)  take((size_t)n_nodes * sizeof(int));
    int*   csr_src   = (int*)  take((size_t)n_edges * sizeof(int));
    const bool have_ws = (off <= ws_size);

    gcn_transpose_w<<<(N_FEATS * N_FEATS) / 256, 256, 0, stream>>>(W, Wt);

    if (have_ws) {
        // ---- CSR build ----
        hipMemsetAsync(deg, 0, (size_t)n_nodes * sizeof(int), stream);
        hipMemsetAsync(cursor, 0, (size_t)n_nodes * sizeof(int), stream);
        gcn_hist<<<(n_edges + 255) / 256, 256, 0, stream>>>(dst, deg, n_edges, n_nodes);
        gcn_scan<<<1, 1024, 0, stream>>>(deg, row_start, n_nodes);
        gcn_build_csr<<<(n_edges + 255) / 256, 256, 0, stream>>>(
            src, dst, row_start, cursor, csr_src, n_edges, n_nodes);
        // ---- pull aggregation (no atomics) ----
        gcn_aggregate<<<(n_nodes + 3) / 4, 256, 0, stream>>>(
            feature, row_start, csr_src, out, n_nodes);
    } else {
        // fallback: atomic scatter
        hipMemsetAsync(d_out, 0, (size_t)n_nodes * N_FEATS * sizeof(float), stream);
        long long total = (long long)n_edges * 32;
        gcn_scatter_add<<<(int)((total + 255) / 256), 256, 0, stream>>>(
            feature, src, dst, out, n_edges, n_nodes);
    }

    // ---- linear layer, in place on d_out ----
    gcn_gemm_inplace<<<(n_nodes + 31) / 32, 256, 0, stream>>>(out, Wt, b, n_nodes);
}

// Round 6
// 186.434 us; speedup vs baseline: 7.4946x; 1.6002x over previous
//
#include <hip/hip_runtime.h>
#include <hip/hip_bf16.h>

#define N_FEATS 128
#define SCAN_CHUNK 1024   // elements per scan block (256 thr x 4)

// ---------------------------------------------------------------------------
// Transpose W [128][128] -> Wt [128][128] (Wt[i][o] = W[o][i])
// ---------------------------------------------------------------------------
__global__ void gcn_transpose_w(const float* __restrict__ W, float* __restrict__ Wt) {
    int t = blockIdx.x * blockDim.x + threadIdx.x;
    int o = t >> 7;
    int i = t & 127;
    Wt[i * N_FEATS + o] = W[o * N_FEATS + i];
}

// ---------------------------------------------------------------------------
// CSR build step 1: degree histogram of dst
// ---------------------------------------------------------------------------
__global__ void gcn_hist(const int* __restrict__ dst, int* __restrict__ deg,
                         int n_edges, int n_nodes) {
    int e = blockIdx.x * blockDim.x + threadIdx.x;
    if (e >= n_edges) return;
    int d = dst[e];
    if ((unsigned)d < (unsigned)n_nodes) atomicAdd(&deg[d], 1);
}

// ---------------------------------------------------------------------------
// Hierarchical scan, phase 1: per-chunk sums. Block b sums deg[b*1024 .. +1024).
// ---------------------------------------------------------------------------
__launch_bounds__(256)
__global__ void gcn_scan_part(const int* __restrict__ deg, int* __restrict__ chunk_sum, int n) {
    const int t = threadIdx.x;
    const int base = blockIdx.x * SCAN_CHUNK;
    int sum = 0;
#pragma unroll
    for (int k = 0; k < 4; ++k) {
        int idx = base + k * 256 + t;            // coalesced
        if (idx < n) sum += deg[idx];
    }
    for (int d = 1; d < 64; d <<= 1) sum += __shfl_xor(sum, d, 64);
    __shared__ int wsum[4];
    if ((t & 63) == 0) wsum[t >> 6] = sum;
    __syncthreads();
    if (t == 0) chunk_sum[blockIdx.x] = wsum[0] + wsum[1] + wsum[2] + wsum[3];
}

// ---------------------------------------------------------------------------
// Phase 2: single small block scans the chunk sums (nchunks ~ 49) ->
// exclusive chunk_off; also writes row_start[n] = grand total.
// ---------------------------------------------------------------------------
__launch_bounds__(256)
__global__ void gcn_scan_chunks(const int* __restrict__ chunk_sum, int* __restrict__ chunk_off,
                                int* __restrict__ row_start, int nchunks, int n) {
    __shared__ int lds[256];
    __shared__ int carry_s;
    const int t = threadIdx.x;
    if (t == 0) carry_s = 0;
    __syncthreads();
    for (int base = 0; base < nchunks; base += 256) {
        int x = (base + t < nchunks) ? chunk_sum[base + t] : 0;
        lds[t] = x;
        __syncthreads();
        for (int off = 1; off < 256; off <<= 1) {
            int v = (t >= off) ? lds[t - off] : 0;
            __syncthreads();
            lds[t] += v;
            __syncthreads();
        }
        int carry = carry_s;
        if (base + t < nchunks) chunk_off[base + t] = carry + lds[t] - x;   // exclusive
        __syncthreads();
        if (t == 255) carry_s = carry + lds[255];
        __syncthreads();
    }
    if (t == 0) row_start[n] = carry_s;
}

// ---------------------------------------------------------------------------
// Phase 3: per-chunk exclusive scan (+ chunk offset) -> row_start.
// Thread handles 4 consecutive elements; wave shfl scan + LDS wave combine.
// ---------------------------------------------------------------------------
__launch_bounds__(256)
__global__ void gcn_scan_final(const int* __restrict__ deg, const int* __restrict__ chunk_off,
                               int* __restrict__ row_start, int n) {
    const int t = threadIdx.x;
    const int base = blockIdx.x * SCAN_CHUNK;
    const int idx0 = base + t * 4;
    int x[4];
#pragma unroll
    for (int k = 0; k < 4; ++k) {
        int idx = idx0 + k;
        x[k] = (idx < n) ? deg[idx] : 0;
    }
    const int tsum = x[0] + x[1] + x[2] + x[3];

    const int lane = t & 63, w = t >> 6;
    int inc = tsum;                               // inclusive scan of thread sums
    for (int d = 1; d < 64; d <<= 1) {
        int v = __shfl_up(inc, d, 64);
        if (lane >= d) inc += v;
    }
    __shared__ int wsum[4];
    if (lane == 63) wsum[w] = inc;
    __syncthreads();
    int woff = 0;
    for (int i = 0; i < w; ++i) woff += wsum[i];

    int run = chunk_off[blockIdx.x] + woff + inc - tsum;   // exclusive prefix
#pragma unroll
    for (int k = 0; k < 4; ++k) {
        int idx = idx0 + k;
        if (idx < n) row_start[idx] = run;
        run += x[k];
    }
}

// ---------------------------------------------------------------------------
// CSR build step 3: scatter src ids into per-dst slots
// ---------------------------------------------------------------------------
__global__ void gcn_build_csr(const int* __restrict__ src, const int* __restrict__ dst,
                              const int* __restrict__ row_start, int* __restrict__ cursor,
                              int* __restrict__ csr_src, int n_edges, int n_nodes) {
    int e = blockIdx.x * blockDim.x + threadIdx.x;
    if (e >= n_edges) return;
    int d = dst[e];
    int s = src[e];
    if ((unsigned)d >= (unsigned)n_nodes || (unsigned)s >= (unsigned)n_nodes) return;
    int pos = atomicAdd(&cursor[d], 1);
    csr_src[row_start[d] + pos] = s;
}

// ---------------------------------------------------------------------------
// Aggregation (pull): one wave per node, lane owns a float2 column slice.
// Edge loop unrolled x4 with independent accumulators -> 4 gathers in flight.
// ---------------------------------------------------------------------------
__launch_bounds__(256)
__global__ void gcn_aggregate(const float* __restrict__ feat,
                              const int* __restrict__ row_start,
                              const int* __restrict__ csr_src,
                              float* __restrict__ out, int n_nodes) {
    int node = blockIdx.x * 4 + (threadIdx.x >> 6);
    if (node >= n_nodes) return;
    int lane = threadIdx.x & 63;
    int beg = row_start[node];
    int end = row_start[node + 1];
    const float2* f2 = reinterpret_cast<const float2*>(feat);

    float2 a0 = make_float2(0.f, 0.f), a1 = a0, a2 = a0, a3 = a0;
    int i = beg;
    for (; i + 4 <= end; i += 4) {
        int s0 = csr_src[i];
        int s1 = csr_src[i + 1];
        int s2 = csr_src[i + 2];
        int s3 = csr_src[i + 3];
        float2 v0 = f2[(size_t)s0 * 64 + lane];
        float2 v1 = f2[(size_t)s1 * 64 + lane];
        float2 v2 = f2[(size_t)s2 * 64 + lane];
        float2 v3 = f2[(size_t)s3 * 64 + lane];
        a0.x += v0.x; a0.y += v0.y;
        a1.x += v1.x; a1.y += v1.y;
        a2.x += v2.x; a2.y += v2.y;
        a3.x += v3.x; a3.y += v3.y;
    }
    for (; i < end; ++i) {
        int s = csr_src[i];
        float2 v = f2[(size_t)s * 64 + lane];
        a0.x += v.x; a0.y += v.y;
    }
    float2 acc = make_float2(a0.x + a1.x + a2.x + a3.x, a0.y + a1.y + a2.y + a3.y);
    reinterpret_cast<float2*>(out)[(size_t)node * 64 + lane] = acc;
}

// ---------------------------------------------------------------------------
// Fallback scatter-add (if ws_size too small for CSR).
// ---------------------------------------------------------------------------
__global__ void gcn_scatter_add(const float* __restrict__ feat,
                                const int* __restrict__ src,
                                const int* __restrict__ dst,
                                float* __restrict__ agg,
                                int n_edges, int n_nodes) {
    long long tid = (long long)blockIdx.x * blockDim.x + threadIdx.x;
    int e = (int)(tid >> 5);
    if (e >= n_edges) return;
    int j = (int)(tid & 31);
    int s = src[e];
    int d = dst[e];
    if ((unsigned)s >= (unsigned)n_nodes || (unsigned)d >= (unsigned)n_nodes) return;
    const float4 v = *reinterpret_cast<const float4*>(feat + (size_t)s * N_FEATS + j * 4);
    float* p = agg + (size_t)d * N_FEATS + j * 4;
    atomicAdd(p + 0, v.x);
    atomicAdd(p + 1, v.y);
    atomicAdd(p + 2, v.z);
    atomicAdd(p + 3, v.w);
}

// ---------------------------------------------------------------------------
// In-place GEMM  out[n][o] = sum_i out[n][i] * Wt[i][o] + b[o]
// ---------------------------------------------------------------------------
__launch_bounds__(256)
__global__ void gcn_gemm_inplace(float* __restrict__ out,
                                 const float* __restrict__ Wt,
                                 const float* __restrict__ b,
                                 int n_nodes) {
    __shared__ float a_lds[32 * N_FEATS];   // 16 KB

    const int t = threadIdx.x;
    const int node0 = blockIdx.x * 32;
    const int rows = min(32, n_nodes - node0);

    float4* a4 = reinterpret_cast<float4*>(a_lds);
    const float4* out4 = reinterpret_cast<const float4*>(out + (size_t)node0 * N_FEATS);
    const int nflt4 = rows * (N_FEATS / 4);
    for (int idx = t; idx < nflt4; idx += 256) a4[idx] = out4[idx];
    __syncthreads();

    const int oq = t & 31;
    const int ng = t >> 5;

    const float4 bb = reinterpret_cast<const float4*>(b)[oq];
    float4 acc[4];
#pragma unroll
    for (int k = 0; k < 4; ++k) acc[k] = bb;

    const float4* Wt4 = reinterpret_cast<const float4*>(Wt);
#pragma unroll 4
    for (int i = 0; i < N_FEATS; ++i) {
        const float4 w = Wt4[i * 32 + oq];
#pragma unroll
        for (int k = 0; k < 4; ++k) {
            const float a = a_lds[(ng * 4 + k) * N_FEATS + i];
            acc[k].x += a * w.x;
            acc[k].y += a * w.y;
            acc[k].z += a * w.z;
            acc[k].w += a * w.w;
        }
    }

    __syncthreads();

#pragma unroll
    for (int k = 0; k < 4; ++k) {
        const int r = ng * 4 + k;
        if (r < rows) {
            reinterpret_cast<float4*>(out + (size_t)(node0 + r) * N_FEATS)[oq] = acc[k];
        }
    }
}

extern "C" void kernel_launch(void* const* d_in, const int* in_sizes, int n_in,
                              void* d_out, int out_size, void* d_ws, size_t ws_size,
                              hipStream_t stream) {
    const float* feature = (const float*)d_in[0];
    const int*   src     = (const int*)d_in[1];
    const int*   dst     = (const int*)d_in[2];
    const float* W       = (const float*)d_in[3];
    const float* b       = (const float*)d_in[4];
    float* out = (float*)d_out;

    const int n_nodes = in_sizes[0] / N_FEATS;
    const int n_edges = in_sizes[1];
    const int nchunks = (n_nodes + SCAN_CHUNK - 1) / SCAN_CHUNK;

    // ---- workspace layout (256 B aligned) ----
    char* ws = (char*)d_ws;
    size_t off = 0;
    auto take = [&](size_t bytes) -> char* {
        char* p = ws + off;
        off = (off + bytes + 255) & ~(size_t)255;
        return p;
    };
    float* Wt        = (float*)take((size_t)N_FEATS * N_FEATS * sizeof(float));
    int*   deg       = (int*)  take((size_t)n_nodes * sizeof(int));
    int*   row_start = (int*)  take(((size_t)n_nodes + 1) * sizeof(int));
    int*   cursor    = (int*)  take((size_t)n_nodes * sizeof(int));
    int*   chunk_sum = (int*)  take((size_t)nchunks * sizeof(int));
    int*   chunk_off = (int*)  take((size_t)nchunks * sizeof(int));
    int*   csr_src   = (int*)  take((size_t)n_edges * sizeof(int));
    const bool have_ws = (off <= ws_size);

    gcn_transpose_w<<<(N_FEATS * N_FEATS) / 256, 256, 0, stream>>>(W, Wt);

    if (have_ws) {
        // ---- CSR build ----
        hipMemsetAsync(deg, 0, (size_t)n_nodes * sizeof(int), stream);
        hipMemsetAsync(cursor, 0, (size_t)n_nodes * sizeof(int), stream);
        gcn_hist<<<(n_edges + 255) / 256, 256, 0, stream>>>(dst, deg, n_edges, n_nodes);
        gcn_scan_part<<<nchunks, 256, 0, stream>>>(deg, chunk_sum, n_nodes);
        gcn_scan_chunks<<<1, 256, 0, stream>>>(chunk_sum, chunk_off, row_start, nchunks, n_nodes);
        gcn_scan_final<<<nchunks, 256, 0, stream>>>(deg, chunk_off, row_start, n_nodes);
        gcn_build_csr<<<(n_edges + 255) / 256, 256, 0, stream>>>(
            src, dst, row_start, cursor, csr_src, n_edges, n_nodes);
        // ---- pull aggregation (no atomics) ----
        gcn_aggregate<<<(n_nodes + 3) / 4, 256, 0, stream>>>(
            feature, row_start, csr_src, out, n_nodes);
    } else {
        // fallback: atomic scatter
        hipMemsetAsync(d_out, 0, (size_t)n_nodes * N_FEATS * sizeof(float), stream);
        long long total = (long long)n_edges * 32;
        gcn_scatter_add<<<(int)((total + 255) / 256), 256, 0, stream>>>(
            feature, src, dst, out, n_edges, n_nodes);
    }

    // ---- linear layer, in place on d_out ----
    gcn_gemm_inplace<<<(n_nodes + 31) / 32, 256, 0, stream>>>(out, Wt, b, n_nodes);
}

// Round 7
// 179.212 us; speedup vs baseline: 7.7966x; 1.0403x over previous
//
#include <hip/hip_runtime.h>
#include <hip/hip_bf16.h>

#define N_FEATS 128
#define SCAN_CHUNK 1024   // elements per scan block (256 thr x 4)

// ---------------------------------------------------------------------------
// Init: transpose W (Wt[i][o] = W[o][i]) and zero deg, one grid-stride kernel.
// ---------------------------------------------------------------------------
__global__ void gcn_init(const float* __restrict__ W, float* __restrict__ Wt,
                         int* __restrict__ deg, int n_nodes) {
    int t = blockIdx.x * blockDim.x + threadIdx.x;
    if (t < N_FEATS * N_FEATS) {
        int o = t >> 7;
        int i = t & 127;
        Wt[i * N_FEATS + o] = W[o * N_FEATS + i];
    }
    int u = t - N_FEATS * N_FEATS;
    if (u >= 0 && u < n_nodes) deg[u] = 0;
}

// ---------------------------------------------------------------------------
// CSR build step 1: degree histogram of dst
// ---------------------------------------------------------------------------
__global__ void gcn_hist(const int* __restrict__ dst, int* __restrict__ deg,
                         int n_edges, int n_nodes) {
    int e = blockIdx.x * blockDim.x + threadIdx.x;
    if (e >= n_edges) return;
    int d = dst[e];
    if ((unsigned)d < (unsigned)n_nodes) atomicAdd(&deg[d], 1);
}

// ---------------------------------------------------------------------------
// Scan phase 1: per-chunk sums. Block b sums deg[b*1024 .. +1024).
// ---------------------------------------------------------------------------
__launch_bounds__(256)
__global__ void gcn_scan_part(const int* __restrict__ deg, int* __restrict__ chunk_sum, int n) {
    const int t = threadIdx.x;
    const int base = blockIdx.x * SCAN_CHUNK;
    int sum = 0;
#pragma unroll
    for (int k = 0; k < 4; ++k) {
        int idx = base + k * 256 + t;            // coalesced
        if (idx < n) sum += deg[idx];
    }
    for (int d = 1; d < 64; d <<= 1) sum += __shfl_xor(sum, d, 64);
    __shared__ int wsum[4];
    if ((t & 63) == 0) wsum[t >> 6] = sum;
    __syncthreads();
    if (t == 0) chunk_sum[blockIdx.x] = wsum[0] + wsum[1] + wsum[2] + wsum[3];
}

// ---------------------------------------------------------------------------
// Scan phase 2 (final): each block computes its chunk offset inline by
// block-reducing chunk_sum[0..b), then does the per-chunk exclusive scan.
// Also zeroes cursor[] and writes row_start[n] (last block).
// ---------------------------------------------------------------------------
__launch_bounds__(256)
__global__ void gcn_scan_final(const int* __restrict__ deg, const int* __restrict__ chunk_sum,
                               int* __restrict__ row_start, int* __restrict__ cursor,
                               int n, int nchunks) {
    const int t = threadIdx.x;
    const int b = blockIdx.x;

    // ---- inline exclusive chunk offset: sum chunk_sum[0..b) ----
    int v = 0;
    for (int j = t; j < b; j += 256) v += chunk_sum[j];
    for (int d = 1; d < 64; d <<= 1) v += __shfl_xor(v, d, 64);
    __shared__ int owsum[4];
    __shared__ int s_off;
    if ((t & 63) == 0) owsum[t >> 6] = v;
    __syncthreads();
    if (t == 0) s_off = owsum[0] + owsum[1] + owsum[2] + owsum[3];
    __syncthreads();
    const int chunk_off = s_off;

    // ---- per-chunk exclusive scan (4 elems / thread) ----
    const int base = b * SCAN_CHUNK;
    const int idx0 = base + t * 4;
    int x[4];
#pragma unroll
    for (int k = 0; k < 4; ++k) {
        int idx = idx0 + k;
        x[k] = (idx < n) ? deg[idx] : 0;
    }
    const int tsum = x[0] + x[1] + x[2] + x[3];

    const int lane = t & 63, w = t >> 6;
    int inc = tsum;                               // inclusive scan of thread sums
    for (int d = 1; d < 64; d <<= 1) {
        int sv = __shfl_up(inc, d, 64);
        if (lane >= d) inc += sv;
    }
    __shared__ int wsum[4];
    if (lane == 63) wsum[w] = inc;
    __syncthreads();
    int woff = 0;
    for (int i = 0; i < w; ++i) woff += wsum[i];

    int run = chunk_off + woff + inc - tsum;      // exclusive prefix
#pragma unroll
    for (int k = 0; k < 4; ++k) {
        int idx = idx0 + k;
        if (idx < n) {
            row_start[idx] = run;
            cursor[idx] = 0;                      // fold cursor memset in here
        }
        run += x[k];
    }

    if (t == 0 && b == nchunks - 1)
        row_start[n] = chunk_off + wsum[0] + wsum[1] + wsum[2] + wsum[3];
}

// ---------------------------------------------------------------------------
// CSR build step 3: scatter src ids into per-dst slots
// ---------------------------------------------------------------------------
__global__ void gcn_build_csr(const int* __restrict__ src, const int* __restrict__ dst,
                              const int* __restrict__ row_start, int* __restrict__ cursor,
                              int* __restrict__ csr_src, int n_edges, int n_nodes) {
    int e = blockIdx.x * blockDim.x + threadIdx.x;
    if (e >= n_edges) return;
    int d = dst[e];
    int s = src[e];
    if ((unsigned)d >= (unsigned)n_nodes || (unsigned)s >= (unsigned)n_nodes) return;
    int pos = atomicAdd(&cursor[d], 1);
    csr_src[row_start[d] + pos] = s;
}

// ---------------------------------------------------------------------------
// Aggregation (pull): one wave per node. Lanes split into two halves; each
// half gathers a DIFFERENT edge's row as float4 (32 lanes x 16B = 512B/row,
// 1KB per wave instruction). 2 pairs unrolled -> 4 edges in flight.
// Final cross-half combine via shfl_xor(32).
// ---------------------------------------------------------------------------
__launch_bounds__(256)
__global__ void gcn_aggregate(const float* __restrict__ feat,
                              const int* __restrict__ row_start,
                              const int* __restrict__ csr_src,
                              float* __restrict__ out, int n_nodes) {
    int node = blockIdx.x * 4 + (threadIdx.x >> 6);
    if (node >= n_nodes) return;
    const int l = threadIdx.x & 63;
    const int q = l & 31;        // float4 column slot within row
    const int h = l >> 5;        // which edge of the pair this half-wave owns
    int beg = row_start[node];
    int end = row_start[node + 1];
    const float4* f4 = reinterpret_cast<const float4*>(feat);

    float4 a0 = make_float4(0.f, 0.f, 0.f, 0.f);
    float4 a1 = a0;
    int i = beg;
    for (; i + 4 <= end; i += 4) {               // 4 edges per iter
        int s0 = csr_src[i + h];
        int s1 = csr_src[i + 2 + h];
        float4 v0 = f4[(size_t)s0 * 32 + q];
        float4 v1 = f4[(size_t)s1 * 32 + q];
        a0.x += v0.x; a0.y += v0.y; a0.z += v0.z; a0.w += v0.w;
        a1.x += v1.x; a1.y += v1.y; a1.z += v1.z; a1.w += v1.w;
    }
    if (i + 2 <= end) {                          // one remaining pair
        int s0 = csr_src[i + h];
        float4 v0 = f4[(size_t)s0 * 32 + q];
        a0.x += v0.x; a0.y += v0.y; a0.z += v0.z; a0.w += v0.w;
        i += 2;
    }
    if (i < end && h == 0) {                     // single leftover edge
        int s = csr_src[i];
        float4 v = f4[(size_t)s * 32 + q];
        a0.x += v.x; a0.y += v.y; a0.z += v.z; a0.w += v.w;
    }

    float4 acc = make_float4(a0.x + a1.x, a0.y + a1.y, a0.z + a1.z, a0.w + a1.w);
    acc.x += __shfl_xor(acc.x, 32, 64);          // combine the two edge-halves
    acc.y += __shfl_xor(acc.y, 32, 64);
    acc.z += __shfl_xor(acc.z, 32, 64);
    acc.w += __shfl_xor(acc.w, 32, 64);

    if (h == 0)
        reinterpret_cast<float4*>(out)[(size_t)node * 32 + q] = acc;
}

// ---------------------------------------------------------------------------
// Fallback scatter-add (if ws_size too small for CSR).
// ---------------------------------------------------------------------------
__global__ void gcn_scatter_add(const float* __restrict__ feat,
                                const int* __restrict__ src,
                                const int* __restrict__ dst,
                                float* __restrict__ agg,
                                int n_edges, int n_nodes) {
    long long tid = (long long)blockIdx.x * blockDim.x + threadIdx.x;
    int e = (int)(tid >> 5);
    if (e >= n_edges) return;
    int j = (int)(tid & 31);
    int s = src[e];
    int d = dst[e];
    if ((unsigned)s >= (unsigned)n_nodes || (unsigned)d >= (unsigned)n_nodes) return;
    const float4 v = *reinterpret_cast<const float4*>(feat + (size_t)s * N_FEATS + j * 4);
    float* p = agg + (size_t)d * N_FEATS + j * 4;
    atomicAdd(p + 0, v.x);
    atomicAdd(p + 1, v.y);
    atomicAdd(p + 2, v.z);
    atomicAdd(p + 3, v.w);
}

// ---------------------------------------------------------------------------
// In-place GEMM  out[n][o] = sum_i out[n][i] * Wt[i][o] + b[o]
// Block = 256 threads, 32 node-rows per block; rows staged to LDS first.
// ---------------------------------------------------------------------------
__launch_bounds__(256)
__global__ void gcn_gemm_inplace(float* __restrict__ out,
                                 const float* __restrict__ Wt,
                                 const float* __restrict__ b,
                                 int n_nodes) {
    __shared__ float a_lds[32 * N_FEATS];   // 16 KB

    const int t = threadIdx.x;
    const int node0 = blockIdx.x * 32;
    const int rows = min(32, n_nodes - node0);

    float4* a4 = reinterpret_cast<float4*>(a_lds);
    const float4* out4 = reinterpret_cast<const float4*>(out + (size_t)node0 * N_FEATS);
    const int nflt4 = rows * (N_FEATS / 4);
    for (int idx = t; idx < nflt4; idx += 256) a4[idx] = out4[idx];
    __syncthreads();

    const int oq = t & 31;
    const int ng = t >> 5;

    const float4 bb = reinterpret_cast<const float4*>(b)[oq];
    float4 acc[4];
#pragma unroll
    for (int k = 0; k < 4; ++k) acc[k] = bb;

    const float4* Wt4 = reinterpret_cast<const float4*>(Wt);
#pragma unroll 4
    for (int i = 0; i < N_FEATS; ++i) {
        const float4 w = Wt4[i * 32 + oq];
#pragma unroll
        for (int k = 0; k < 4; ++k) {
            const float a = a_lds[(ng * 4 + k) * N_FEATS + i];
            acc[k].x += a * w.x;
            acc[k].y += a * w.y;
            acc[k].z += a * w.z;
            acc[k].w += a * w.w;
        }
    }

    __syncthreads();

#pragma unroll
    for (int k = 0; k < 4; ++k) {
        const int r = ng * 4 + k;
        if (r < rows) {
            reinterpret_cast<float4*>(out + (size_t)(node0 + r) * N_FEATS)[oq] = acc[k];
        }
    }
}

extern "C" void kernel_launch(void* const* d_in, const int* in_sizes, int n_in,
                              void* d_out, int out_size, void* d_ws, size_t ws_size,
                              hipStream_t stream) {
    const float* feature = (const float*)d_in[0];
    const int*   src     = (const int*)d_in[1];
    const int*   dst     = (const int*)d_in[2];
    const float* W       = (const float*)d_in[3];
    const float* b       = (const float*)d_in[4];
    float* out = (float*)d_out;

    const int n_nodes = in_sizes[0] / N_FEATS;
    const int n_edges = in_sizes[1];
    const int nchunks = (n_nodes + SCAN_CHUNK - 1) / SCAN_CHUNK;

    // ---- workspace layout (256 B aligned) ----
    char* ws = (char*)d_ws;
    size_t off = 0;
    auto take = [&](size_t bytes) -> char* {
        char* p = ws + off;
        off = (off + bytes + 255) & ~(size_t)255;
        return p;
    };
    float* Wt        = (float*)take((size_t)N_FEATS * N_FEATS * sizeof(float));
    int*   deg       = (int*)  take((size_t)n_nodes * sizeof(int));
    int*   row_start = (int*)  take(((size_t)n_nodes + 1) * sizeof(int));
    int*   cursor    = (int*)  take((size_t)n_nodes * sizeof(int));
    int*   chunk_sum = (int*)  take((size_t)nchunks * sizeof(int));
    int*   csr_src   = (int*)  take((size_t)n_edges * sizeof(int));
    const bool have_ws = (off <= ws_size);

    if (have_ws) {
        // ---- init (transpose W + zero deg) ----
        int init_elems = N_FEATS * N_FEATS + n_nodes;
        gcn_init<<<(init_elems + 255) / 256, 256, 0, stream>>>(W, Wt, deg, n_nodes);
        // ---- CSR build ----
        gcn_hist<<<(n_edges + 255) / 256, 256, 0, stream>>>(dst, deg, n_edges, n_nodes);
        gcn_scan_part<<<nchunks, 256, 0, stream>>>(deg, chunk_sum, n_nodes);
        gcn_scan_final<<<nchunks, 256, 0, stream>>>(deg, chunk_sum, row_start, cursor,
                                                    n_nodes, nchunks);
        gcn_build_csr<<<(n_edges + 255) / 256, 256, 0, stream>>>(
            src, dst, row_start, cursor, csr_src, n_edges, n_nodes);
        // ---- pull aggregation (no atomics) ----
        gcn_aggregate<<<(n_nodes + 3) / 4, 256, 0, stream>>>(
            feature, row_start, csr_src, out, n_nodes);
    } else {
        // fallback: atomic scatter
        gcn_init<<<(N_FEATS * N_FEATS + 255) / 256, 256, 0, stream>>>(W, Wt, deg, 0);
        hipMemsetAsync(d_out, 0, (size_t)n_nodes * N_FEATS * sizeof(float), stream);
        long long total = (long long)n_edges * 32;
        gcn_scatter_add<<<(int)((total + 255) / 256), 256, 0, stream>>>(
            feature, src, dst, out, n_edges, n_nodes);
    }

    // ---- linear layer, in place on d_out ----
    gcn_gemm_inplace<<<(n_nodes + 31) / 32, 256, 0, stream>>>(out, Wt, b, n_nodes);
}

// Round 8
// 150.669 us; speedup vs baseline: 9.2736x; 1.1894x over previous
//
#include <hip/hip_runtime.h>
#include <hip/hip_bf16.h>

#define N_FEATS 128
#define SCAN_CHUNK 1024   // elements per scan block (256 thr x 4)

// ---------------------------------------------------------------------------
// Init: transpose W (Wt[i][o] = W[o][i]) and zero deg, one kernel.
// ---------------------------------------------------------------------------
__global__ void gcn_init(const float* __restrict__ W, float* __restrict__ Wt,
                         int* __restrict__ deg, int n_nodes) {
    int t = blockIdx.x * blockDim.x + threadIdx.x;
    if (t < N_FEATS * N_FEATS) {
        int o = t >> 7;
        int i = t & 127;
        Wt[i * N_FEATS + o] = W[o * N_FEATS + i];
    }
    int u = t - N_FEATS * N_FEATS;
    if (u >= 0 && u < n_nodes) deg[u] = 0;
}

// ---------------------------------------------------------------------------
// CSR build pass 1 (tier A): histogram AND per-edge slot position.
// Guards BOTH indices so every counted slot is later written exactly once.
// ---------------------------------------------------------------------------
__global__ void gcn_hist_pos(const int* __restrict__ src, const int* __restrict__ dst,
                             int* __restrict__ deg, int* __restrict__ pos,
                             int n_edges, int n_nodes) {
    int e = blockIdx.x * blockDim.x + threadIdx.x;
    if (e >= n_edges) return;
    int d = dst[e];
    int s = src[e];
    if ((unsigned)d < (unsigned)n_nodes && (unsigned)s < (unsigned)n_nodes)
        pos[e] = atomicAdd(&deg[d], 1);
}

// Tier B histogram (no pos array needed)
__global__ void gcn_hist(const int* __restrict__ src, const int* __restrict__ dst,
                         int* __restrict__ deg, int n_edges, int n_nodes) {
    int e = blockIdx.x * blockDim.x + threadIdx.x;
    if (e >= n_edges) return;
    int d = dst[e];
    int s = src[e];
    if ((unsigned)d < (unsigned)n_nodes && (unsigned)s < (unsigned)n_nodes)
        atomicAdd(&deg[d], 1);
}

// ---------------------------------------------------------------------------
// Scan phase 1: per-chunk sums.
// ---------------------------------------------------------------------------
__launch_bounds__(256)
__global__ void gcn_scan_part(const int* __restrict__ deg, int* __restrict__ chunk_sum, int n) {
    const int t = threadIdx.x;
    const int base = blockIdx.x * SCAN_CHUNK;
    int sum = 0;
#pragma unroll
    for (int k = 0; k < 4; ++k) {
        int idx = base + k * 256 + t;
        if (idx < n) sum += deg[idx];
    }
    for (int d = 1; d < 64; d <<= 1) sum += __shfl_xor(sum, d, 64);
    __shared__ int wsum[4];
    if ((t & 63) == 0) wsum[t >> 6] = sum;
    __syncthreads();
    if (t == 0) chunk_sum[blockIdx.x] = wsum[0] + wsum[1] + wsum[2] + wsum[3];
}

// ---------------------------------------------------------------------------
// Scan phase 2: per-block inline chunk offset + per-chunk exclusive scan.
// Optionally zeroes cursor (tier B). Last block writes row_start[n].
// ---------------------------------------------------------------------------
__launch_bounds__(256)
__global__ void gcn_scan_final(const int* __restrict__ deg, const int* __restrict__ chunk_sum,
                               int* __restrict__ row_start, int* __restrict__ cursor,
                               int n, int nchunks) {
    const int t = threadIdx.x;
    const int b = blockIdx.x;

    int v = 0;
    for (int j = t; j < b; j += 256) v += chunk_sum[j];
    for (int d = 1; d < 64; d <<= 1) v += __shfl_xor(v, d, 64);
    __shared__ int owsum[4];
    __shared__ int s_off;
    if ((t & 63) == 0) owsum[t >> 6] = v;
    __syncthreads();
    if (t == 0) s_off = owsum[0] + owsum[1] + owsum[2] + owsum[3];
    __syncthreads();
    const int chunk_off = s_off;

    const int base = b * SCAN_CHUNK;
    const int idx0 = base + t * 4;
    int x[4];
#pragma unroll
    for (int k = 0; k < 4; ++k) {
        int idx = idx0 + k;
        x[k] = (idx < n) ? deg[idx] : 0;
    }
    const int tsum = x[0] + x[1] + x[2] + x[3];

    const int lane = t & 63, w = t >> 6;
    int inc = tsum;
    for (int d = 1; d < 64; d <<= 1) {
        int sv = __shfl_up(inc, d, 64);
        if (lane >= d) inc += sv;
    }
    __shared__ int wsum[4];
    if (lane == 63) wsum[w] = inc;
    __syncthreads();
    int woff = 0;
    for (int i = 0; i < w; ++i) woff += wsum[i];

    int run = chunk_off + woff + inc - tsum;
#pragma unroll
    for (int k = 0; k < 4; ++k) {
        int idx = idx0 + k;
        if (idx < n) {
            row_start[idx] = run;
            if (cursor) cursor[idx] = 0;
        }
        run += x[k];
    }

    if (t == 0 && b == nchunks - 1)
        row_start[n] = chunk_off + wsum[0] + wsum[1] + wsum[2] + wsum[3];
}

// ---------------------------------------------------------------------------
// CSR scatter, tier A: atomic-free (uses precomputed pos).
// ---------------------------------------------------------------------------
__global__ void gcn_build_csr_pos(const int* __restrict__ src, const int* __restrict__ dst,
                                  const int* __restrict__ row_start, const int* __restrict__ pos,
                                  int* __restrict__ csr_src, int n_edges, int n_nodes) {
    int e = blockIdx.x * blockDim.x + threadIdx.x;
    if (e >= n_edges) return;
    int d = dst[e];
    int s = src[e];
    if ((unsigned)d >= (unsigned)n_nodes || (unsigned)s >= (unsigned)n_nodes) return;
    csr_src[row_start[d] + pos[e]] = s;
}

// CSR scatter, tier B: atomic cursor.
__global__ void gcn_build_csr(const int* __restrict__ src, const int* __restrict__ dst,
                              const int* __restrict__ row_start, int* __restrict__ cursor,
                              int* __restrict__ csr_src, int n_edges, int n_nodes) {
    int e = blockIdx.x * blockDim.x + threadIdx.x;
    if (e >= n_edges) return;
    int d = dst[e];
    int s = src[e];
    if ((unsigned)d >= (unsigned)n_nodes || (unsigned)s >= (unsigned)n_nodes) return;
    int p = atomicAdd(&cursor[d], 1);
    csr_src[row_start[d] + p] = s;
}

// ---------------------------------------------------------------------------
// Aggregation (pull): one wave per node, half-waves own alternate edges,
// 4 independent float4 accumulators each -> 8 edge-rows in flight per wave.
// ---------------------------------------------------------------------------
__launch_bounds__(256)
__global__ void gcn_aggregate(const float* __restrict__ feat,
                              const int* __restrict__ row_start,
                              const int* __restrict__ csr_src,
                              float* __restrict__ out, int n_nodes) {
    int node = blockIdx.x * 4 + (threadIdx.x >> 6);
    if (node >= n_nodes) return;
    const int l = threadIdx.x & 63;
    const int q = l & 31;        // float4 column slot within row
    const int h = l >> 5;        // which edge of each pair this half-wave owns
    int beg = row_start[node];
    int end = row_start[node + 1];
    const float4* f4 = reinterpret_cast<const float4*>(feat);

    float4 a0 = make_float4(0.f, 0.f, 0.f, 0.f);
    float4 a1 = a0, a2 = a0, a3 = a0;
    int i = beg;
    for (; i + 8 <= end; i += 8) {               // 8 edges per iter
        int s0 = csr_src[i + h];
        int s1 = csr_src[i + 2 + h];
        int s2 = csr_src[i + 4 + h];
        int s3 = csr_src[i + 6 + h];
        float4 v0 = f4[(size_t)s0 * 32 + q];
        float4 v1 = f4[(size_t)s1 * 32 + q];
        float4 v2 = f4[(size_t)s2 * 32 + q];
        float4 v3 = f4[(size_t)s3 * 32 + q];
        a0.x += v0.x; a0.y += v0.y; a0.z += v0.z; a0.w += v0.w;
        a1.x += v1.x; a1.y += v1.y; a1.z += v1.z; a1.w += v1.w;
        a2.x += v2.x; a2.y += v2.y; a2.z += v2.z; a2.w += v2.w;
        a3.x += v3.x; a3.y += v3.y; a3.z += v3.z; a3.w += v3.w;
    }
    for (; i + 2 <= end; i += 2) {               // remaining pairs (<=3)
        int s0 = csr_src[i + h];
        float4 v0 = f4[(size_t)s0 * 32 + q];
        a0.x += v0.x; a0.y += v0.y; a0.z += v0.z; a0.w += v0.w;
    }
    if (i < end && h == 0) {                     // single leftover edge
        int s = csr_src[i];
        float4 v = f4[(size_t)s * 32 + q];
        a0.x += v.x; a0.y += v.y; a0.z += v.z; a0.w += v.w;
    }

    float4 acc = make_float4(a0.x + a1.x + a2.x + a3.x,
                             a0.y + a1.y + a2.y + a3.y,
                             a0.z + a1.z + a2.z + a3.z,
                             a0.w + a1.w + a2.w + a3.w);
    acc.x += __shfl_xor(acc.x, 32, 64);
    acc.y += __shfl_xor(acc.y, 32, 64);
    acc.z += __shfl_xor(acc.z, 32, 64);
    acc.w += __shfl_xor(acc.w, 32, 64);

    if (h == 0)
        reinterpret_cast<float4*>(out)[(size_t)node * 32 + q] = acc;
}

// ---------------------------------------------------------------------------
// Fallback scatter-add (tier C).
// ---------------------------------------------------------------------------
__global__ void gcn_scatter_add(const float* __restrict__ feat,
                                const int* __restrict__ src,
                                const int* __restrict__ dst,
                                float* __restrict__ agg,
                                int n_edges, int n_nodes) {
    long long tid = (long long)blockIdx.x * blockDim.x + threadIdx.x;
    int e = (int)(tid >> 5);
    if (e >= n_edges) return;
    int j = (int)(tid & 31);
    int s = src[e];
    int d = dst[e];
    if ((unsigned)s >= (unsigned)n_nodes || (unsigned)d >= (unsigned)n_nodes) return;
    const float4 v = *reinterpret_cast<const float4*>(feat + (size_t)s * N_FEATS + j * 4);
    float* p = agg + (size_t)d * N_FEATS + j * 4;
    atomicAdd(p + 0, v.x);
    atomicAdd(p + 1, v.y);
    atomicAdd(p + 2, v.z);
    atomicAdd(p + 3, v.w);
}

// ---------------------------------------------------------------------------
// In-place GEMM  out[n][o] = sum_i out[n][i] * Wt[i][o] + b[o]
// ---------------------------------------------------------------------------
__launch_bounds__(256)
__global__ void gcn_gemm_inplace(float* __restrict__ out,
                                 const float* __restrict__ Wt,
                                 const float* __restrict__ b,
                                 int n_nodes) {
    __shared__ float a_lds[32 * N_FEATS];   // 16 KB

    const int t = threadIdx.x;
    const int node0 = blockIdx.x * 32;
    const int rows = min(32, n_nodes - node0);

    float4* a4 = reinterpret_cast<float4*>(a_lds);
    const float4* out4 = reinterpret_cast<const float4*>(out + (size_t)node0 * N_FEATS);
    const int nflt4 = rows * (N_FEATS / 4);
    for (int idx = t; idx < nflt4; idx += 256) a4[idx] = out4[idx];
    __syncthreads();

    const int oq = t & 31;
    const int ng = t >> 5;

    const float4 bb = reinterpret_cast<const float4*>(b)[oq];
    float4 acc[4];
#pragma unroll
    for (int k = 0; k < 4; ++k) acc[k] = bb;

    const float4* Wt4 = reinterpret_cast<const float4*>(Wt);
#pragma unroll 4
    for (int i = 0; i < N_FEATS; ++i) {
        const float4 w = Wt4[i * 32 + oq];
#pragma unroll
        for (int k = 0; k < 4; ++k) {
            const float a = a_lds[(ng * 4 + k) * N_FEATS + i];
            acc[k].x += a * w.x;
            acc[k].y += a * w.y;
            acc[k].z += a * w.z;
            acc[k].w += a * w.w;
        }
    }

    __syncthreads();

#pragma unroll
    for (int k = 0; k < 4; ++k) {
        const int r = ng * 4 + k;
        if (r < rows) {
            reinterpret_cast<float4*>(out + (size_t)(node0 + r) * N_FEATS)[oq] = acc[k];
        }
    }
}

extern "C" void kernel_launch(void* const* d_in, const int* in_sizes, int n_in,
                              void* d_out, int out_size, void* d_ws, size_t ws_size,
                              hipStream_t stream) {
    const float* feature = (const float*)d_in[0];
    const int*   src     = (const int*)d_in[1];
    const int*   dst     = (const int*)d_in[2];
    const float* W       = (const float*)d_in[3];
    const float* b       = (const float*)d_in[4];
    float* out = (float*)d_out;

    const int n_nodes = in_sizes[0] / N_FEATS;
    const int n_edges = in_sizes[1];
    const int nchunks = (n_nodes + SCAN_CHUNK - 1) / SCAN_CHUNK;

    // ---- workspace layout (256 B aligned) ----
    char* ws = (char*)d_ws;
    size_t off = 0;
    auto take = [&](size_t bytes) -> char* {
        char* p = ws + off;
        off = (off + bytes + 255) & ~(size_t)255;
        return p;
    };
    // common
    float* Wt        = (float*)take((size_t)N_FEATS * N_FEATS * sizeof(float));
    int*   deg       = (int*)  take((size_t)n_nodes * sizeof(int));
    int*   row_start = (int*)  take(((size_t)n_nodes + 1) * sizeof(int));
    int*   chunk_sum = (int*)  take((size_t)nchunks * sizeof(int));
    int*   csr_src   = (int*)  take((size_t)n_edges * sizeof(int));
    const size_t off_common = off;
    // tier A extra: pos[n_edges]; tier B extra: cursor[n_nodes]
    int* pos    = (int*)take((size_t)n_edges * sizeof(int));
    const bool tierA = (off <= ws_size);
    off = off_common;
    int* cursor = (int*)take((size_t)n_nodes * sizeof(int));
    const bool tierB = !tierA && (off <= ws_size);

    if (tierA || tierB) {
        int init_elems = N_FEATS * N_FEATS + n_nodes;
        gcn_init<<<(init_elems + 255) / 256, 256, 0, stream>>>(W, Wt, deg, n_nodes);
        const int eblocks = (n_edges + 255) / 256;
        if (tierA) {
            gcn_hist_pos<<<eblocks, 256, 0, stream>>>(src, dst, deg, pos, n_edges, n_nodes);
        } else {
            gcn_hist<<<eblocks, 256, 0, stream>>>(src, dst, deg, n_edges, n_nodes);
        }
        gcn_scan_part<<<nchunks, 256, 0, stream>>>(deg, chunk_sum, n_nodes);
        gcn_scan_final<<<nchunks, 256, 0, stream>>>(deg, chunk_sum, row_start,
                                                    tierA ? (int*)nullptr : cursor,
                                                    n_nodes, nchunks);
        if (tierA) {
            gcn_build_csr_pos<<<eblocks, 256, 0, stream>>>(
                src, dst, row_start, pos, csr_src, n_edges, n_nodes);
        } else {
            gcn_build_csr<<<eblocks, 256, 0, stream>>>(
                src, dst, row_start, cursor, csr_src, n_edges, n_nodes);
        }
        gcn_aggregate<<<(n_nodes + 3) / 4, 256, 0, stream>>>(
            feature, row_start, csr_src, out, n_nodes);
    } else {
        // tier C: atomic scatter
        gcn_init<<<(N_FEATS * N_FEATS + 255) / 256, 256, 0, stream>>>(W, Wt, deg, 0);
        hipMemsetAsync(d_out, 0, (size_t)n_nodes * N_FEATS * sizeof(float), stream);
        long long total = (long long)n_edges * 32;
        gcn_scatter_add<<<(int)((total + 255) / 256), 256, 0, stream>>>(
            feature, src, dst, out, n_edges, n_nodes);
    }

    gcn_gemm_inplace<<<(n_nodes + 31) / 32, 256, 0, stream>>>(out, Wt, b, n_nodes);
}

// Round 9
// 133.427 us; speedup vs baseline: 10.4720x; 1.1292x over previous
//
#include <hip/hip_runtime.h>
#include <hip/hip_bf16.h>

#define N_FEATS 128
#define SCAN_CHUNK 1024   // elements per scan block (256 thr x 4)

__device__ __forceinline__ unsigned short f32_to_bf16_rne(float f) {
    unsigned u = __float_as_uint(f);
    u = u + 0x7FFFu + ((u >> 16) & 1u);   // round-to-nearest-even
    return (unsigned short)(u >> 16);
}

// ---------------------------------------------------------------------------
// Init: cast feature f32->bf16 (8 elems/thread), transpose W, zero deg.
// featb==nullptr skips the cast (fp32 tiers).
// ---------------------------------------------------------------------------
__global__ void gcn_init(const float* __restrict__ W, float* __restrict__ Wt,
                         const float* __restrict__ feat, unsigned short* __restrict__ featb,
                         int cast_chunks, int* __restrict__ deg, int n_nodes) {
    int t = blockIdx.x * blockDim.x + threadIdx.x;
    if (t < cast_chunks) {                       // cast: 8 floats -> 8 bf16
        const float4* f4 = reinterpret_cast<const float4*>(feat) + (size_t)t * 2;
        float4 x0 = f4[0];
        float4 x1 = f4[1];
        ushort4 o0, o1;
        o0.x = f32_to_bf16_rne(x0.x); o0.y = f32_to_bf16_rne(x0.y);
        o0.z = f32_to_bf16_rne(x0.z); o0.w = f32_to_bf16_rne(x0.w);
        o1.x = f32_to_bf16_rne(x1.x); o1.y = f32_to_bf16_rne(x1.y);
        o1.z = f32_to_bf16_rne(x1.z); o1.w = f32_to_bf16_rne(x1.w);
        reinterpret_cast<ushort4*>(featb)[(size_t)t * 2 + 0] = o0;
        reinterpret_cast<ushort4*>(featb)[(size_t)t * 2 + 1] = o1;
    }
    int t2 = t - cast_chunks;
    if (t2 >= 0 && t2 < N_FEATS * N_FEATS) {     // transpose W
        int o = t2 >> 7;
        int i = t2 & 127;
        Wt[i * N_FEATS + o] = W[o * N_FEATS + i];
    }
    int u = t2 - N_FEATS * N_FEATS;
    if (u >= 0 && u < n_nodes) deg[u] = 0;       // zero deg
}

// ---------------------------------------------------------------------------
// CSR pass 1: histogram AND per-edge slot position (guards both indices).
// ---------------------------------------------------------------------------
__global__ void gcn_hist_pos(const int* __restrict__ src, const int* __restrict__ dst,
                             int* __restrict__ deg, int* __restrict__ pos,
                             int n_edges, int n_nodes) {
    int e = blockIdx.x * blockDim.x + threadIdx.x;
    if (e >= n_edges) return;
    int d = dst[e];
    int s = src[e];
    if ((unsigned)d < (unsigned)n_nodes && (unsigned)s < (unsigned)n_nodes)
        pos[e] = atomicAdd(&deg[d], 1);
}

// Tier B histogram (no pos array)
__global__ void gcn_hist(const int* __restrict__ src, const int* __restrict__ dst,
                         int* __restrict__ deg, int n_edges, int n_nodes) {
    int e = blockIdx.x * blockDim.x + threadIdx.x;
    if (e >= n_edges) return;
    int d = dst[e];
    int s = src[e];
    if ((unsigned)d < (unsigned)n_nodes && (unsigned)s < (unsigned)n_nodes)
        atomicAdd(&deg[d], 1);
}

// ---------------------------------------------------------------------------
// Scan phase 1: per-chunk sums.
// ---------------------------------------------------------------------------
__launch_bounds__(256)
__global__ void gcn_scan_part(const int* __restrict__ deg, int* __restrict__ chunk_sum, int n) {
    const int t = threadIdx.x;
    const int base = blockIdx.x * SCAN_CHUNK;
    int sum = 0;
#pragma unroll
    for (int k = 0; k < 4; ++k) {
        int idx = base + k * 256 + t;
        if (idx < n) sum += deg[idx];
    }
    for (int d = 1; d < 64; d <<= 1) sum += __shfl_xor(sum, d, 64);
    __shared__ int wsum[4];
    if ((t & 63) == 0) wsum[t >> 6] = sum;
    __syncthreads();
    if (t == 0) chunk_sum[blockIdx.x] = wsum[0] + wsum[1] + wsum[2] + wsum[3];
}

// ---------------------------------------------------------------------------
// Scan phase 2: inline chunk offset + per-chunk exclusive scan.
// Optionally zeroes cursor (tier B). Last block writes row_start[n].
// ---------------------------------------------------------------------------
__launch_bounds__(256)
__global__ void gcn_scan_final(const int* __restrict__ deg, const int* __restrict__ chunk_sum,
                               int* __restrict__ row_start, int* __restrict__ cursor,
                               int n, int nchunks) {
    const int t = threadIdx.x;
    const int b = blockIdx.x;

    int v = 0;
    for (int j = t; j < b; j += 256) v += chunk_sum[j];
    for (int d = 1; d < 64; d <<= 1) v += __shfl_xor(v, d, 64);
    __shared__ int owsum[4];
    __shared__ int s_off;
    if ((t & 63) == 0) owsum[t >> 6] = v;
    __syncthreads();
    if (t == 0) s_off = owsum[0] + owsum[1] + owsum[2] + owsum[3];
    __syncthreads();
    const int chunk_off = s_off;

    const int base = b * SCAN_CHUNK;
    const int idx0 = base + t * 4;
    int x[4];
#pragma unroll
    for (int k = 0; k < 4; ++k) {
        int idx = idx0 + k;
        x[k] = (idx < n) ? deg[idx] : 0;
    }
    const int tsum = x[0] + x[1] + x[2] + x[3];

    const int lane = t & 63, w = t >> 6;
    int inc = tsum;
    for (int d = 1; d < 64; d <<= 1) {
        int sv = __shfl_up(inc, d, 64);
        if (lane >= d) inc += sv;
    }
    __shared__ int wsum[4];
    if (lane == 63) wsum[w] = inc;
    __syncthreads();
    int woff = 0;
    for (int i = 0; i < w; ++i) woff += wsum[i];

    int run = chunk_off + woff + inc - tsum;
#pragma unroll
    for (int k = 0; k < 4; ++k) {
        int idx = idx0 + k;
        if (idx < n) {
            row_start[idx] = run;
            if (cursor) cursor[idx] = 0;
        }
        run += x[k];
    }

    if (t == 0 && b == nchunks - 1)
        row_start[n] = chunk_off + wsum[0] + wsum[1] + wsum[2] + wsum[3];
}

// ---------------------------------------------------------------------------
// CSR scatter, atomic-free (uses precomputed pos).
// ---------------------------------------------------------------------------
__global__ void gcn_build_csr_pos(const int* __restrict__ src, const int* __restrict__ dst,
                                  const int* __restrict__ row_start, const int* __restrict__ pos,
                                  int* __restrict__ csr_src, int n_edges, int n_nodes) {
    int e = blockIdx.x * blockDim.x + threadIdx.x;
    if (e >= n_edges) return;
    int d = dst[e];
    int s = src[e];
    if ((unsigned)d >= (unsigned)n_nodes || (unsigned)s >= (unsigned)n_nodes) return;
    csr_src[row_start[d] + pos[e]] = s;
}

// CSR scatter, atomic cursor (tier B).
__global__ void gcn_build_csr(const int* __restrict__ src, const int* __restrict__ dst,
                              const int* __restrict__ row_start, int* __restrict__ cursor,
                              int* __restrict__ csr_src, int n_edges, int n_nodes) {
    int e = blockIdx.x * blockDim.x + threadIdx.x;
    if (e >= n_edges) return;
    int d = dst[e];
    int s = src[e];
    if ((unsigned)d >= (unsigned)n_nodes || (unsigned)s >= (unsigned)n_nodes) return;
    int p = atomicAdd(&cursor[d], 1);
    csr_src[row_start[d] + p] = s;
}

// ---------------------------------------------------------------------------
// bf16 aggregation (tier A2): one wave per node. Quarter-wave (16 lanes x
// 16B = 256B) per edge-row, 4 edges per instruction, x4 unroll = 16 edges
// in flight. fp32 accumulate; cross-quarter combine via shfl_xor 16/32.
// ---------------------------------------------------------------------------
#define BACC(acc, v)                                              \
    do {                                                          \
        unsigned uu;                                              \
        uu = (v).x;                                               \
        acc[0] += __uint_as_float(uu << 16);                      \
        acc[1] += __uint_as_float(uu & 0xFFFF0000u);              \
        uu = (v).y;                                               \
        acc[2] += __uint_as_float(uu << 16);                      \
        acc[3] += __uint_as_float(uu & 0xFFFF0000u);              \
        uu = (v).z;                                               \
        acc[4] += __uint_as_float(uu << 16);                      \
        acc[5] += __uint_as_float(uu & 0xFFFF0000u);              \
        uu = (v).w;                                               \
        acc[6] += __uint_as_float(uu << 16);                      \
        acc[7] += __uint_as_float(uu & 0xFFFF0000u);              \
    } while (0)

__launch_bounds__(256)
__global__ void gcn_aggregate_bf16(const uint4* __restrict__ featb,
                                   const int* __restrict__ row_start,
                                   const int* __restrict__ csr_src,
                                   float* __restrict__ out, int n_nodes) {
    int node = blockIdx.x * 4 + (threadIdx.x >> 6);
    if (node >= n_nodes) return;
    const int l = threadIdx.x & 63;
    const int qw = l >> 4;       // quarter-wave 0..3 (edge slot)
    const int ql = l & 15;       // 16B chunk within the 256B row
    int beg = row_start[node];
    int end = row_start[node + 1];

    float a0[8] = {0,0,0,0,0,0,0,0};
    float a1[8] = {0,0,0,0,0,0,0,0};
    float a2[8] = {0,0,0,0,0,0,0,0};
    float a3[8] = {0,0,0,0,0,0,0,0};

    int i = beg;
    for (; i + 16 <= end; i += 16) {             // 16 edges per iter
        int s0 = csr_src[i + qw];
        int s1 = csr_src[i + 4 + qw];
        int s2 = csr_src[i + 8 + qw];
        int s3 = csr_src[i + 12 + qw];
        uint4 v0 = featb[(size_t)s0 * 16 + ql];
        uint4 v1 = featb[(size_t)s1 * 16 + ql];
        uint4 v2 = featb[(size_t)s2 * 16 + ql];
        uint4 v3 = featb[(size_t)s3 * 16 + ql];
        BACC(a0, v0);
        BACC(a1, v1);
        BACC(a2, v2);
        BACC(a3, v3);
    }
    for (; i + 4 <= end; i += 4) {               // groups of 4 (<=3 iters)
        int s = csr_src[i + qw];
        uint4 v = featb[(size_t)s * 16 + ql];
        BACC(a0, v);
    }
    int rem = end - i;                           // <4 leftover edges
    if (qw < rem) {
        int s = csr_src[i + qw];
        uint4 v = featb[(size_t)s * 16 + ql];
        BACC(a0, v);
    }

    float r[8];
#pragma unroll
    for (int k = 0; k < 8; ++k) {
        r[k] = a0[k] + a1[k] + a2[k] + a3[k];
        r[k] += __shfl_xor(r[k], 16, 64);
        r[k] += __shfl_xor(r[k], 32, 64);
    }

    if (qw == 0) {                               // lanes 0..15 write the row
        float4* o4 = reinterpret_cast<float4*>(out + (size_t)node * N_FEATS + ql * 8);
        o4[0] = make_float4(r[0], r[1], r[2], r[3]);
        o4[1] = make_float4(r[4], r[5], r[6], r[7]);
    }
}

// ---------------------------------------------------------------------------
// fp32 aggregation (tier A/B fallback): half-wave float4, 8 edges in flight.
// ---------------------------------------------------------------------------
__launch_bounds__(256)
__global__ void gcn_aggregate(const float* __restrict__ feat,
                              const int* __restrict__ row_start,
                              const int* __restrict__ csr_src,
                              float* __restrict__ out, int n_nodes) {
    int node = blockIdx.x * 4 + (threadIdx.x >> 6);
    if (node >= n_nodes) return;
    const int l = threadIdx.x & 63;
    const int q = l & 31;
    const int h = l >> 5;
    int beg = row_start[node];
    int end = row_start[node + 1];
    const float4* f4 = reinterpret_cast<const float4*>(feat);

    float4 a0 = make_float4(0.f, 0.f, 0.f, 0.f);
    float4 a1 = a0, a2 = a0, a3 = a0;
    int i = beg;
    for (; i + 8 <= end; i += 8) {
        int s0 = csr_src[i + h];
        int s1 = csr_src[i + 2 + h];
        int s2 = csr_src[i + 4 + h];
        int s3 = csr_src[i + 6 + h];
        float4 v0 = f4[(size_t)s0 * 32 + q];
        float4 v1 = f4[(size_t)s1 * 32 + q];
        float4 v2 = f4[(size_t)s2 * 32 + q];
        float4 v3 = f4[(size_t)s3 * 32 + q];
        a0.x += v0.x; a0.y += v0.y; a0.z += v0.z; a0.w += v0.w;
        a1.x += v1.x; a1.y += v1.y; a1.z += v1.z; a1.w += v1.w;
        a2.x += v2.x; a2.y += v2.y; a2.z += v2.z; a2.w += v2.w;
        a3.x += v3.x; a3.y += v3.y; a3.z += v3.z; a3.w += v3.w;
    }
    for (; i + 2 <= end; i += 2) {
        int s0 = csr_src[i + h];
        float4 v0 = f4[(size_t)s0 * 32 + q];
        a0.x += v0.x; a0.y += v0.y; a0.z += v0.z; a0.w += v0.w;
    }
    if (i < end && h == 0) {
        int s = csr_src[i];
        float4 v = f4[(size_t)s * 32 + q];
        a0.x += v.x; a0.y += v.y; a0.z += v.z; a0.w += v.w;
    }

    float4 acc = make_float4(a0.x + a1.x + a2.x + a3.x,
                             a0.y + a1.y + a2.y + a3.y,
                             a0.z + a1.z + a2.z + a3.z,
                             a0.w + a1.w + a2.w + a3.w);
    acc.x += __shfl_xor(acc.x, 32, 64);
    acc.y += __shfl_xor(acc.y, 32, 64);
    acc.z += __shfl_xor(acc.z, 32, 64);
    acc.w += __shfl_xor(acc.w, 32, 64);

    if (h == 0)
        reinterpret_cast<float4*>(out)[(size_t)node * 32 + q] = acc;
}

// ---------------------------------------------------------------------------
// Fallback scatter-add (tier C).
// ---------------------------------------------------------------------------
__global__ void gcn_scatter_add(const float* __restrict__ feat,
                                const int* __restrict__ src,
                                const int* __restrict__ dst,
                                float* __restrict__ agg,
                                int n_edges, int n_nodes) {
    long long tid = (long long)blockIdx.x * blockDim.x + threadIdx.x;
    int e = (int)(tid >> 5);
    if (e >= n_edges) return;
    int j = (int)(tid & 31);
    int s = src[e];
    int d = dst[e];
    if ((unsigned)s >= (unsigned)n_nodes || (unsigned)d >= (unsigned)n_nodes) return;
    const float4 v = *reinterpret_cast<const float4*>(feat + (size_t)s * N_FEATS + j * 4);
    float* p = agg + (size_t)d * N_FEATS + j * 4;
    atomicAdd(p + 0, v.x);
    atomicAdd(p + 1, v.y);
    atomicAdd(p + 2, v.z);
    atomicAdd(p + 3, v.w);
}

// ---------------------------------------------------------------------------
// In-place GEMM  out[n][o] = sum_i out[n][i] * Wt[i][o] + b[o]
// ---------------------------------------------------------------------------
__launch_bounds__(256)
__global__ void gcn_gemm_inplace(float* __restrict__ out,
                                 const float* __restrict__ Wt,
                                 const float* __restrict__ b,
                                 int n_nodes) {
    __shared__ float a_lds[32 * N_FEATS];   // 16 KB

    const int t = threadIdx.x;
    const int node0 = blockIdx.x * 32;
    const int rows = min(32, n_nodes - node0);

    float4* a4 = reinterpret_cast<float4*>(a_lds);
    const float4* out4 = reinterpret_cast<const float4*>(out + (size_t)node0 * N_FEATS);
    const int nflt4 = rows * (N_FEATS / 4);
    for (int idx = t; idx < nflt4; idx += 256) a4[idx] = out4[idx];
    __syncthreads();

    const int oq = t & 31;
    const int ng = t >> 5;

    const float4 bb = reinterpret_cast<const float4*>(b)[oq];
    float4 acc[4];
#pragma unroll
    for (int k = 0; k < 4; ++k) acc[k] = bb;

    const float4* Wt4 = reinterpret_cast<const float4*>(Wt);
#pragma unroll 4
    for (int i = 0; i < N_FEATS; ++i) {
        const float4 w = Wt4[i * 32 + oq];
#pragma unroll
        for (int k = 0; k < 4; ++k) {
            const float a = a_lds[(ng * 4 + k) * N_FEATS + i];
            acc[k].x += a * w.x;
            acc[k].y += a * w.y;
            acc[k].z += a * w.z;
            acc[k].w += a * w.w;
        }
    }

    __syncthreads();

#pragma unroll
    for (int k = 0; k < 4; ++k) {
        const int r = ng * 4 + k;
        if (r < rows) {
            reinterpret_cast<float4*>(out + (size_t)(node0 + r) * N_FEATS)[oq] = acc[k];
        }
    }
}

extern "C" void kernel_launch(void* const* d_in, const int* in_sizes, int n_in,
                              void* d_out, int out_size, void* d_ws, size_t ws_size,
                              hipStream_t stream) {
    const float* feature = (const float*)d_in[0];
    const int*   src     = (const int*)d_in[1];
    const int*   dst     = (const int*)d_in[2];
    const float* W       = (const float*)d_in[3];
    const float* b       = (const float*)d_in[4];
    float* out = (float*)d_out;

    const int n_nodes = in_sizes[0] / N_FEATS;
    const int n_edges = in_sizes[1];
    const int nchunks = (n_nodes + SCAN_CHUNK - 1) / SCAN_CHUNK;

    // ---- workspace layout (256 B aligned) ----
    char* ws = (char*)d_ws;
    size_t off = 0;
    auto take = [&](size_t bytes) -> char* {
        char* p = ws + off;
        off = (off + bytes + 255) & ~(size_t)255;
        return p;
    };
    // common
    float* Wt        = (float*)take((size_t)N_FEATS * N_FEATS * sizeof(float));
    int*   deg       = (int*)  take((size_t)n_nodes * sizeof(int));
    int*   row_start = (int*)  take(((size_t)n_nodes + 1) * sizeof(int));
    int*   chunk_sum = (int*)  take((size_t)nchunks * sizeof(int));
    int*   csr_src   = (int*)  take((size_t)n_edges * sizeof(int));
    const size_t off_common = off;

    // tier A2: bf16 feature + pos
    unsigned short* featb = (unsigned short*)take((size_t)n_nodes * N_FEATS * sizeof(unsigned short));
    int* posA2 = (int*)take((size_t)n_edges * sizeof(int));
    const bool tierA2 = (off <= ws_size);
    // tier A: pos only
    off = off_common;
    int* posA = (int*)take((size_t)n_edges * sizeof(int));
    const bool tierA = !tierA2 && (off <= ws_size);
    // tier B: cursor only
    off = off_common;
    int* cursor = (int*)take((size_t)n_nodes * sizeof(int));
    const bool tierB = !tierA2 && !tierA && (off <= ws_size);

    if (tierA2 || tierA || tierB) {
        const int cast_chunks = tierA2 ? (n_nodes * (N_FEATS / 8)) : 0;
        const int init_elems = cast_chunks + N_FEATS * N_FEATS + n_nodes;
        gcn_init<<<(init_elems + 255) / 256, 256, 0, stream>>>(
            W, Wt, feature, featb, cast_chunks, deg, n_nodes);

        const int eblocks = (n_edges + 255) / 256;
        int* pos = tierA2 ? posA2 : posA;
        if (tierA2 || tierA) {
            gcn_hist_pos<<<eblocks, 256, 0, stream>>>(src, dst, deg, pos, n_edges, n_nodes);
        } else {
            gcn_hist<<<eblocks, 256, 0, stream>>>(src, dst, deg, n_edges, n_nodes);
        }
        gcn_scan_part<<<nchunks, 256, 0, stream>>>(deg, chunk_sum, n_nodes);
        gcn_scan_final<<<nchunks, 256, 0, stream>>>(deg, chunk_sum, row_start,
                                                    (tierA2 || tierA) ? (int*)nullptr : cursor,
                                                    n_nodes, nchunks);
        if (tierA2 || tierA) {
            gcn_build_csr_pos<<<eblocks, 256, 0, stream>>>(
                src, dst, row_start, pos, csr_src, n_edges, n_nodes);
        } else {
            gcn_build_csr<<<eblocks, 256, 0, stream>>>(
                src, dst, row_start, cursor, csr_src, n_edges, n_nodes);
        }
        if (tierA2) {
            gcn_aggregate_bf16<<<(n_nodes + 3) / 4, 256, 0, stream>>>(
                reinterpret_cast<const uint4*>(featb), row_start, csr_src, out, n_nodes);
        } else {
            gcn_aggregate<<<(n_nodes + 3) / 4, 256, 0, stream>>>(
                feature, row_start, csr_src, out, n_nodes);
        }
    } else {
        // tier C: atomic scatter
        gcn_init<<<(N_FEATS * N_FEATS + 255) / 256, 256, 0, stream>>>(
            W, Wt, feature, (unsigned short*)nullptr, 0, deg, 0);
        hipMemsetAsync(d_out, 0, (size_t)n_nodes * N_FEATS * sizeof(float), stream);
        long long total = (long long)n_edges * 32;
        gcn_scatter_add<<<(int)((total + 255) / 256), 256, 0, stream>>>(
            feature, src, dst, out, n_edges, n_nodes);
    }

    gcn_gemm_inplace<<<(n_nodes + 31) / 32, 256, 0, stream>>>(out, Wt, b, n_nodes);
}

// Round 10
// 124.856 us; speedup vs baseline: 11.1909x; 1.0686x over previous
//
#include <hip/hip_runtime.h>
#include <hip/hip_bf16.h>

#define N_FEATS 128
#define SCAN_CHUNK 1024   // elements per scan block (256 thr x 4)

typedef __attribute__((ext_vector_type(8))) short bf16x8;
typedef __attribute__((ext_vector_type(4))) float f32x4;

__device__ __forceinline__ unsigned short f32_to_bf16_rne(float f) {
    unsigned u = __float_as_uint(f);
    u = u + 0x7FFFu + ((u >> 16) & 1u);   // round-to-nearest-even
    return (unsigned short)(u >> 16);
}

// ---------------------------------------------------------------------------
// Init: cast feature f32->bf16, cast W f32->bf16 (tier A2), transpose W
// (fallback tiers), zero deg. One kernel, disjoint index ranges.
// ---------------------------------------------------------------------------
__global__ void gcn_init(const float* __restrict__ W, float* __restrict__ Wt,
                         const float* __restrict__ feat, unsigned short* __restrict__ featb,
                         int cast_chunks, unsigned short* __restrict__ Wb,
                         int* __restrict__ deg, int n_nodes) {
    int t = blockIdx.x * blockDim.x + threadIdx.x;
    if (t < cast_chunks) {                       // feature: 8 floats -> 8 bf16
        const float4* f4 = reinterpret_cast<const float4*>(feat) + (size_t)t * 2;
        float4 x0 = f4[0];
        float4 x1 = f4[1];
        ushort4 o0, o1;
        o0.x = f32_to_bf16_rne(x0.x); o0.y = f32_to_bf16_rne(x0.y);
        o0.z = f32_to_bf16_rne(x0.z); o0.w = f32_to_bf16_rne(x0.w);
        o1.x = f32_to_bf16_rne(x1.x); o1.y = f32_to_bf16_rne(x1.y);
        o1.z = f32_to_bf16_rne(x1.z); o1.w = f32_to_bf16_rne(x1.w);
        reinterpret_cast<ushort4*>(featb)[(size_t)t * 2 + 0] = o0;
        reinterpret_cast<ushort4*>(featb)[(size_t)t * 2 + 1] = o1;
    }
    int t2 = t - cast_chunks;
    const int wcast = (Wb != nullptr) ? (N_FEATS * N_FEATS / 8) : 0;
    if (t2 >= 0 && t2 < wcast) {                 // W: 8 floats -> 8 bf16
        const float4* f4 = reinterpret_cast<const float4*>(W) + (size_t)t2 * 2;
        float4 x0 = f4[0];
        float4 x1 = f4[1];
        ushort4 o0, o1;
        o0.x = f32_to_bf16_rne(x0.x); o0.y = f32_to_bf16_rne(x0.y);
        o0.z = f32_to_bf16_rne(x0.z); o0.w = f32_to_bf16_rne(x0.w);
        o1.x = f32_to_bf16_rne(x1.x); o1.y = f32_to_bf16_rne(x1.y);
        o1.z = f32_to_bf16_rne(x1.z); o1.w = f32_to_bf16_rne(x1.w);
        reinterpret_cast<ushort4*>(Wb)[(size_t)t2 * 2 + 0] = o0;
        reinterpret_cast<ushort4*>(Wb)[(size_t)t2 * 2 + 1] = o1;
    }
    int t3 = t2 - wcast;
    if (t3 >= 0 && t3 < N_FEATS * N_FEATS) {     // transpose W (fp32 fallback GEMM)
        int o = t3 >> 7;
        int i = t3 & 127;
        Wt[i * N_FEATS + o] = W[o * N_FEATS + i];
    }
    int u = t3 - N_FEATS * N_FEATS;
    if (u >= 0 && u < n_nodes) deg[u] = 0;       // zero deg
}

// ---------------------------------------------------------------------------
// CSR pass 1: histogram AND per-edge slot position (guards both indices).
// ---------------------------------------------------------------------------
__global__ void gcn_hist_pos(const int* __restrict__ src, const int* __restrict__ dst,
                             int* __restrict__ deg, int* __restrict__ pos,
                             int n_edges, int n_nodes) {
    int e = blockIdx.x * blockDim.x + threadIdx.x;
    if (e >= n_edges) return;
    int d = dst[e];
    int s = src[e];
    if ((unsigned)d < (unsigned)n_nodes && (unsigned)s < (unsigned)n_nodes)
        pos[e] = atomicAdd(&deg[d], 1);
}

// Tier B histogram (no pos array)
__global__ void gcn_hist(const int* __restrict__ src, const int* __restrict__ dst,
                         int* __restrict__ deg, int n_edges, int n_nodes) {
    int e = blockIdx.x * blockDim.x + threadIdx.x;
    if (e >= n_edges) return;
    int d = dst[e];
    int s = src[e];
    if ((unsigned)d < (unsigned)n_nodes && (unsigned)s < (unsigned)n_nodes)
        atomicAdd(&deg[d], 1);
}

// ---------------------------------------------------------------------------
// Scan phase 1: per-chunk sums.
// ---------------------------------------------------------------------------
__launch_bounds__(256)
__global__ void gcn_scan_part(const int* __restrict__ deg, int* __restrict__ chunk_sum, int n) {
    const int t = threadIdx.x;
    const int base = blockIdx.x * SCAN_CHUNK;
    int sum = 0;
#pragma unroll
    for (int k = 0; k < 4; ++k) {
        int idx = base + k * 256 + t;
        if (idx < n) sum += deg[idx];
    }
    for (int d = 1; d < 64; d <<= 1) sum += __shfl_xor(sum, d, 64);
    __shared__ int wsum[4];
    if ((t & 63) == 0) wsum[t >> 6] = sum;
    __syncthreads();
    if (t == 0) chunk_sum[blockIdx.x] = wsum[0] + wsum[1] + wsum[2] + wsum[3];
}

// ---------------------------------------------------------------------------
// Scan phase 2: inline chunk offset + per-chunk exclusive scan.
// Optionally zeroes cursor (tier B). Last block writes row_start[n].
// ---------------------------------------------------------------------------
__launch_bounds__(256)
__global__ void gcn_scan_final(const int* __restrict__ deg, const int* __restrict__ chunk_sum,
                               int* __restrict__ row_start, int* __restrict__ cursor,
                               int n, int nchunks) {
    const int t = threadIdx.x;
    const int b = blockIdx.x;

    int v = 0;
    for (int j = t; j < b; j += 256) v += chunk_sum[j];
    for (int d = 1; d < 64; d <<= 1) v += __shfl_xor(v, d, 64);
    __shared__ int owsum[4];
    __shared__ int s_off;
    if ((t & 63) == 0) owsum[t >> 6] = v;
    __syncthreads();
    if (t == 0) s_off = owsum[0] + owsum[1] + owsum[2] + owsum[3];
    __syncthreads();
    const int chunk_off = s_off;

    const int base = b * SCAN_CHUNK;
    const int idx0 = base + t * 4;
    int x[4];
#pragma unroll
    for (int k = 0; k < 4; ++k) {
        int idx = idx0 + k;
        x[k] = (idx < n) ? deg[idx] : 0;
    }
    const int tsum = x[0] + x[1] + x[2] + x[3];

    const int lane = t & 63, w = t >> 6;
    int inc = tsum;
    for (int d = 1; d < 64; d <<= 1) {
        int sv = __shfl_up(inc, d, 64);
        if (lane >= d) inc += sv;
    }
    __shared__ int wsum[4];
    if (lane == 63) wsum[w] = inc;
    __syncthreads();
    int woff = 0;
    for (int i = 0; i < w; ++i) woff += wsum[i];

    int run = chunk_off + woff + inc - tsum;
#pragma unroll
    for (int k = 0; k < 4; ++k) {
        int idx = idx0 + k;
        if (idx < n) {
            row_start[idx] = run;
            if (cursor) cursor[idx] = 0;
        }
        run += x[k];
    }

    if (t == 0 && b == nchunks - 1)
        row_start[n] = chunk_off + wsum[0] + wsum[1] + wsum[2] + wsum[3];
}

// ---------------------------------------------------------------------------
// CSR scatter, atomic-free (uses precomputed pos).
// ---------------------------------------------------------------------------
__global__ void gcn_build_csr_pos(const int* __restrict__ src, const int* __restrict__ dst,
                                  const int* __restrict__ row_start, const int* __restrict__ pos,
                                  int* __restrict__ csr_src, int n_edges, int n_nodes) {
    int e = blockIdx.x * blockDim.x + threadIdx.x;
    if (e >= n_edges) return;
    int d = dst[e];
    int s = src[e];
    if ((unsigned)d >= (unsigned)n_nodes || (unsigned)s >= (unsigned)n_nodes) return;
    csr_src[row_start[d] + pos[e]] = s;
}

// CSR scatter, atomic cursor (tier B).
__global__ void gcn_build_csr(const int* __restrict__ src, const int* __restrict__ dst,
                              const int* __restrict__ row_start, int* __restrict__ cursor,
                              int* __restrict__ csr_src, int n_edges, int n_nodes) {
    int e = blockIdx.x * blockDim.x + threadIdx.x;
    if (e >= n_edges) return;
    int d = dst[e];
    int s = src[e];
    if ((unsigned)d >= (unsigned)n_nodes || (unsigned)s >= (unsigned)n_nodes) return;
    int p = atomicAdd(&cursor[d], 1);
    csr_src[row_start[d] + p] = s;
}

// ---------------------------------------------------------------------------
// bf16 aggregation (tier A2): one wave per node, quarter-wave per edge-row,
// 16 edges in flight, fp32 accumulate, cross-quarter shfl combine.
// ---------------------------------------------------------------------------
#define BACC(acc, v)                                              \
    do {                                                          \
        unsigned uu;                                              \
        uu = (v).x;                                               \
        acc[0] += __uint_as_float(uu << 16);                      \
        acc[1] += __uint_as_float(uu & 0xFFFF0000u);              \
        uu = (v).y;                                               \
        acc[2] += __uint_as_float(uu << 16);                      \
        acc[3] += __uint_as_float(uu & 0xFFFF0000u);              \
        uu = (v).z;                                               \
        acc[4] += __uint_as_float(uu << 16);                      \
        acc[5] += __uint_as_float(uu & 0xFFFF0000u);              \
        uu = (v).w;                                               \
        acc[6] += __uint_as_float(uu << 16);                      \
        acc[7] += __uint_as_float(uu & 0xFFFF0000u);              \
    } while (0)

__launch_bounds__(256)
__global__ void gcn_aggregate_bf16(const uint4* __restrict__ featb,
                                   const int* __restrict__ row_start,
                                   const int* __restrict__ csr_src,
                                   float* __restrict__ out, int n_nodes) {
    int node = blockIdx.x * 4 + (threadIdx.x >> 6);
    if (node >= n_nodes) return;
    const int l = threadIdx.x & 63;
    const int qw = l >> 4;       // quarter-wave 0..3 (edge slot)
    const int ql = l & 15;       // 16B chunk within the 256B row
    int beg = row_start[node];
    int end = row_start[node + 1];

    float a0[8] = {0,0,0,0,0,0,0,0};
    float a1[8] = {0,0,0,0,0,0,0,0};
    float a2[8] = {0,0,0,0,0,0,0,0};
    float a3[8] = {0,0,0,0,0,0,0,0};

    int i = beg;
    for (; i + 16 <= end; i += 16) {             // 16 edges per iter
        int s0 = csr_src[i + qw];
        int s1 = csr_src[i + 4 + qw];
        int s2 = csr_src[i + 8 + qw];
        int s3 = csr_src[i + 12 + qw];
        uint4 v0 = featb[(size_t)s0 * 16 + ql];
        uint4 v1 = featb[(size_t)s1 * 16 + ql];
        uint4 v2 = featb[(size_t)s2 * 16 + ql];
        uint4 v3 = featb[(size_t)s3 * 16 + ql];
        BACC(a0, v0);
        BACC(a1, v1);
        BACC(a2, v2);
        BACC(a3, v3);
    }
    for (; i + 4 <= end; i += 4) {               // groups of 4 (<=3 iters)
        int s = csr_src[i + qw];
        uint4 v = featb[(size_t)s * 16 + ql];
        BACC(a0, v);
    }
    int rem = end - i;                           // <4 leftover edges
    if (qw < rem) {
        int s = csr_src[i + qw];
        uint4 v = featb[(size_t)s * 16 + ql];
        BACC(a0, v);
    }

    float r[8];
#pragma unroll
    for (int k = 0; k < 8; ++k) {
        r[k] = a0[k] + a1[k] + a2[k] + a3[k];
        r[k] += __shfl_xor(r[k], 16, 64);
        r[k] += __shfl_xor(r[k], 32, 64);
    }

    if (qw == 0) {                               // lanes 0..15 write the row
        float4* o4 = reinterpret_cast<float4*>(out + (size_t)node * N_FEATS + ql * 8);
        o4[0] = make_float4(r[0], r[1], r[2], r[3]);
        o4[1] = make_float4(r[4], r[5], r[6], r[7]);
    }
}

// ---------------------------------------------------------------------------
// fp32 aggregation (tier A/B fallback): half-wave float4, 8 edges in flight.
// ---------------------------------------------------------------------------
__launch_bounds__(256)
__global__ void gcn_aggregate(const float* __restrict__ feat,
                              const int* __restrict__ row_start,
                              const int* __restrict__ csr_src,
                              float* __restrict__ out, int n_nodes) {
    int node = blockIdx.x * 4 + (threadIdx.x >> 6);
    if (node >= n_nodes) return;
    const int l = threadIdx.x & 63;
    const int q = l & 31;
    const int h = l >> 5;
    int beg = row_start[node];
    int end = row_start[node + 1];
    const float4* f4 = reinterpret_cast<const float4*>(feat);

    float4 a0 = make_float4(0.f, 0.f, 0.f, 0.f);
    float4 a1 = a0, a2 = a0, a3 = a0;
    int i = beg;
    for (; i + 8 <= end; i += 8) {
        int s0 = csr_src[i + h];
        int s1 = csr_src[i + 2 + h];
        int s2 = csr_src[i + 4 + h];
        int s3 = csr_src[i + 6 + h];
        float4 v0 = f4[(size_t)s0 * 32 + q];
        float4 v1 = f4[(size_t)s1 * 32 + q];
        float4 v2 = f4[(size_t)s2 * 32 + q];
        float4 v3 = f4[(size_t)s3 * 32 + q];
        a0.x += v0.x; a0.y += v0.y; a0.z += v0.z; a0.w += v0.w;
        a1.x += v1.x; a1.y += v1.y; a1.z += v1.z; a1.w += v1.w;
        a2.x += v2.x; a2.y += v2.y; a2.z += v2.z; a2.w += v2.w;
        a3.x += v3.x; a3.y += v3.y; a3.z += v3.z; a3.w += v3.w;
    }
    for (; i + 2 <= end; i += 2) {
        int s0 = csr_src[i + h];
        float4 v0 = f4[(size_t)s0 * 32 + q];
        a0.x += v0.x; a0.y += v0.y; a0.z += v0.z; a0.w += v0.w;
    }
    if (i < end && h == 0) {
        int s = csr_src[i];
        float4 v = f4[(size_t)s * 32 + q];
        a0.x += v.x; a0.y += v.y; a0.z += v.z; a0.w += v.w;
    }

    float4 acc = make_float4(a0.x + a1.x + a2.x + a3.x,
                             a0.y + a1.y + a2.y + a3.y,
                             a0.z + a1.z + a2.z + a3.z,
                             a0.w + a1.w + a2.w + a3.w);
    acc.x += __shfl_xor(acc.x, 32, 64);
    acc.y += __shfl_xor(acc.y, 32, 64);
    acc.z += __shfl_xor(acc.z, 32, 64);
    acc.w += __shfl_xor(acc.w, 32, 64);

    if (h == 0)
        reinterpret_cast<float4*>(out)[(size_t)node * 32 + q] = acc;
}

// ---------------------------------------------------------------------------
// Fallback scatter-add (tier C).
// ---------------------------------------------------------------------------
__global__ void gcn_scatter_add(const float* __restrict__ feat,
                                const int* __restrict__ src,
                                const int* __restrict__ dst,
                                float* __restrict__ agg,
                                int n_edges, int n_nodes) {
    long long tid = (long long)blockIdx.x * blockDim.x + threadIdx.x;
    int e = (int)(tid >> 5);
    if (e >= n_edges) return;
    int j = (int)(tid & 31);
    int s = src[e];
    int d = dst[e];
    if ((unsigned)s >= (unsigned)n_nodes || (unsigned)d >= (unsigned)n_nodes) return;
    const float4 v = *reinterpret_cast<const float4*>(feat + (size_t)s * N_FEATS + j * 4);
    float* p = agg + (size_t)d * N_FEATS + j * 4;
    atomicAdd(p + 0, v.x);
    atomicAdd(p + 1, v.y);
    atomicAdd(p + 2, v.z);
    atomicAdd(p + 3, v.w);
}

// ---------------------------------------------------------------------------
// MFMA GEMM (tier A2), in place on d_out:
//   out[m][n] = sum_k out[m][k] * W[n][k] + b[n]
// One wave per 16-row stripe. A: fp32 rows of out, cast inline to bf16.
// B: Wb (bf16 W, [o][i] layout) -> B[k][n] = W[n][k], lane reads row n=l&15,
// 8 consecutive k. 8 ntiles x 4 K-steps of mfma_f32_16x16x32_bf16.
// C/D layout (m89-verified): col = lane&15, row = (lane>>4)*4 + reg.
// In-place safe: all A loads complete before epilogue stores; waves own
// disjoint row stripes.
// ---------------------------------------------------------------------------
__launch_bounds__(256)
__global__ void gcn_gemm_mfma(float* __restrict__ out,
                              const unsigned short* __restrict__ Wb,
                              const float* __restrict__ bias,
                              int n_nodes) {
    const long long gtid = (long long)blockIdx.x * blockDim.x + threadIdx.x;
    const int wave = (int)(gtid >> 6);
    const int row0 = wave * 16;
    if (row0 >= n_nodes) return;
    const int l = (int)(threadIdx.x & 63);
    const int lr = l & 15;        // A row within stripe / B,D column
    const int kb = l >> 4;        // k-block 0..3 (8 k each)

    // ---- A frags: row row0+lr, inline fp32 -> bf16 cast ----
    bf16x8 afrag[4] = {};
    if (row0 + lr < n_nodes) {
        const float* aptr = out + (size_t)(row0 + lr) * N_FEATS + kb * 8;
#pragma unroll
        for (int kk = 0; kk < 4; ++kk) {
            float4 x0 = *reinterpret_cast<const float4*>(aptr + kk * 32);
            float4 x1 = *reinterpret_cast<const float4*>(aptr + kk * 32 + 4);
            bf16x8 af;
            af[0] = (short)f32_to_bf16_rne(x0.x);
            af[1] = (short)f32_to_bf16_rne(x0.y);
            af[2] = (short)f32_to_bf16_rne(x0.z);
            af[3] = (short)f32_to_bf16_rne(x0.w);
            af[4] = (short)f32_to_bf16_rne(x1.x);
            af[5] = (short)f32_to_bf16_rne(x1.y);
            af[6] = (short)f32_to_bf16_rne(x1.z);
            af[7] = (short)f32_to_bf16_rne(x1.w);
            afrag[kk] = af;
        }
    }

    f32x4 acc[8];
#pragma unroll
    for (int nt = 0; nt < 8; ++nt) acc[nt] = (f32x4){0.f, 0.f, 0.f, 0.f};

#pragma unroll
    for (int nt = 0; nt < 8; ++nt) {
        const unsigned short* wp = Wb + (size_t)(nt * 16 + lr) * N_FEATS + kb * 8;
#pragma unroll
        for (int kk = 0; kk < 4; ++kk) {
            bf16x8 bfrag = *reinterpret_cast<const bf16x8*>(wp + kk * 32);
            acc[nt] = __builtin_amdgcn_mfma_f32_16x16x32_bf16(afrag[kk], bfrag, acc[nt], 0, 0, 0);
        }
    }

    // ---- epilogue: bias + store fp32 ----
#pragma unroll
    for (int nt = 0; nt < 8; ++nt) {
        const int col = nt * 16 + lr;
        const float bb = bias[col];
#pragma unroll
        for (int j = 0; j < 4; ++j) {
            const int r = row0 + kb * 4 + j;
            if (r < n_nodes)
                out[(size_t)r * N_FEATS + col] = acc[nt][j] + bb;
        }
    }
}

// ---------------------------------------------------------------------------
// fp32 VALU GEMM (fallback tiers), in place on d_out.
// ---------------------------------------------------------------------------
__launch_bounds__(256)
__global__ void gcn_gemm_inplace(float* __restrict__ out,
                                 const float* __restrict__ Wt,
                                 const float* __restrict__ b,
                                 int n_nodes) {
    __shared__ float a_lds[32 * N_FEATS];   // 16 KB

    const int t = threadIdx.x;
    const int node0 = blockIdx.x * 32;
    const int rows = min(32, n_nodes - node0);

    float4* a4 = reinterpret_cast<float4*>(a_lds);
    const float4* out4 = reinterpret_cast<const float4*>(out + (size_t)node0 * N_FEATS);
    const int nflt4 = rows * (N_FEATS / 4);
    for (int idx = t; idx < nflt4; idx += 256) a4[idx] = out4[idx];
    __syncthreads();

    const int oq = t & 31;
    const int ng = t >> 5;

    const float4 bb = reinterpret_cast<const float4*>(b)[oq];
    float4 acc[4];
#pragma unroll
    for (int k = 0; k < 4; ++k) acc[k] = bb;

    const float4* Wt4 = reinterpret_cast<const float4*>(Wt);
#pragma unroll 4
    for (int i = 0; i < N_FEATS; ++i) {
        const float4 w = Wt4[i * 32 + oq];
#pragma unroll
        for (int k = 0; k < 4; ++k) {
            const float a = a_lds[(ng * 4 + k) * N_FEATS + i];
            acc[k].x += a * w.x;
            acc[k].y += a * w.y;
            acc[k].z += a * w.z;
            acc[k].w += a * w.w;
        }
    }

    __syncthreads();

#pragma unroll
    for (int k = 0; k < 4; ++k) {
        const int r = ng * 4 + k;
        if (r < rows) {
            reinterpret_cast<float4*>(out + (size_t)(node0 + r) * N_FEATS)[oq] = acc[k];
        }
    }
}

extern "C" void kernel_launch(void* const* d_in, const int* in_sizes, int n_in,
                              void* d_out, int out_size, void* d_ws, size_t ws_size,
                              hipStream_t stream) {
    const float* feature = (const float*)d_in[0];
    const int*   src     = (const int*)d_in[1];
    const int*   dst     = (const int*)d_in[2];
    const float* W       = (const float*)d_in[3];
    const float* b       = (const float*)d_in[4];
    float* out = (float*)d_out;

    const int n_nodes = in_sizes[0] / N_FEATS;
    const int n_edges = in_sizes[1];
    const int nchunks = (n_nodes + SCAN_CHUNK - 1) / SCAN_CHUNK;

    // ---- workspace layout (256 B aligned) ----
    char* ws = (char*)d_ws;
    size_t off = 0;
    auto take = [&](size_t bytes) -> char* {
        char* p = ws + off;
        off = (off + bytes + 255) & ~(size_t)255;
        return p;
    };
    // common
    float* Wt        = (float*)take((size_t)N_FEATS * N_FEATS * sizeof(float));
    int*   deg       = (int*)  take((size_t)n_nodes * sizeof(int));
    int*   row_start = (int*)  take(((size_t)n_nodes + 1) * sizeof(int));
    int*   chunk_sum = (int*)  take((size_t)nchunks * sizeof(int));
    int*   csr_src   = (int*)  take((size_t)n_edges * sizeof(int));
    const size_t off_common = off;

    // tier A2: bf16 feature + bf16 W + pos
    unsigned short* featb = (unsigned short*)take((size_t)n_nodes * N_FEATS * sizeof(unsigned short));
    unsigned short* Wb    = (unsigned short*)take((size_t)N_FEATS * N_FEATS * sizeof(unsigned short));
    int* posA2 = (int*)take((size_t)n_edges * sizeof(int));
    const bool tierA2 = (off <= ws_size);
    // tier A: pos only
    off = off_common;
    int* posA = (int*)take((size_t)n_edges * sizeof(int));
    const bool tierA = !tierA2 && (off <= ws_size);
    // tier B: cursor only
    off = off_common;
    int* cursor = (int*)take((size_t)n_nodes * sizeof(int));
    const bool tierB = !tierA2 && !tierA && (off <= ws_size);

    if (tierA2 || tierA || tierB) {
        const int cast_chunks = tierA2 ? (n_nodes * (N_FEATS / 8)) : 0;
        const int wcast = tierA2 ? (N_FEATS * N_FEATS / 8) : 0;
        const int init_elems = cast_chunks + wcast + N_FEATS * N_FEATS + n_nodes;
        gcn_init<<<(init_elems + 255) / 256, 256, 0, stream>>>(
            W, Wt, feature, featb, cast_chunks,
            tierA2 ? Wb : (unsigned short*)nullptr, deg, n_nodes);

        const int eblocks = (n_edges + 255) / 256;
        int* pos = tierA2 ? posA2 : posA;
        if (tierA2 || tierA) {
            gcn_hist_pos<<<eblocks, 256, 0, stream>>>(src, dst, deg, pos, n_edges, n_nodes);
        } else {
            gcn_hist<<<eblocks, 256, 0, stream>>>(src, dst, deg, n_edges, n_nodes);
        }
        gcn_scan_part<<<nchunks, 256, 0, stream>>>(deg, chunk_sum, n_nodes);
        gcn_scan_final<<<nchunks, 256, 0, stream>>>(deg, chunk_sum, row_start,
                                                    (tierA2 || tierA) ? (int*)nullptr : cursor,
                                                    n_nodes, nchunks);
        if (tierA2 || tierA) {
            gcn_build_csr_pos<<<eblocks, 256, 0, stream>>>(
                src, dst, row_start, pos, csr_src, n_edges, n_nodes);
        } else {
            gcn_build_csr<<<eblocks, 256, 0, stream>>>(
                src, dst, row_start, cursor, csr_src, n_edges, n_nodes);
        }
        if (tierA2) {
            gcn_aggregate_bf16<<<(n_nodes + 3) / 4, 256, 0, stream>>>(
                reinterpret_cast<const uint4*>(featb), row_start, csr_src, out, n_nodes);
        } else {
            gcn_aggregate<<<(n_nodes + 3) / 4, 256, 0, stream>>>(
                feature, row_start, csr_src, out, n_nodes);
        }
    } else {
        // tier C: atomic scatter
        gcn_init<<<(N_FEATS * N_FEATS + 255) / 256, 256, 0, stream>>>(
            W, Wt, feature, (unsigned short*)nullptr, 0, (unsigned short*)nullptr, deg, 0);
        hipMemsetAsync(d_out, 0, (size_t)n_nodes * N_FEATS * sizeof(float), stream);
        long long total = (long long)n_edges * 32;
        gcn_scatter_add<<<(int)((total + 255) / 256), 256, 0, stream>>>(
            feature, src, dst, out, n_edges, n_nodes);
    }

    // ---- linear layer, in place on d_out ----
    if (tierA2) {
        const long long nthr = (long long)((n_nodes + 15) / 16) * 64;
        gcn_gemm_mfma<<<(int)((nthr + 255) / 256), 256, 0, stream>>>(out, Wb, b, n_nodes);
    } else {
        gcn_gemm_inplace<<<(n_nodes + 31) / 32, 256, 0, stream>>>(out, Wt, b, n_nodes);
    }
}

// Round 11
// 124.008 us; speedup vs baseline: 11.2674x; 1.0068x over previous
//
#include <hip/hip_runtime.h>
#include <hip/hip_bf16.h>

#define N_FEATS 128
#define SCAN_CHUNK 1024   // elements per scan block (256 thr x 4)

typedef __attribute__((ext_vector_type(8))) short bf16x8;
typedef __attribute__((ext_vector_type(4))) float f32x4;

__device__ __forceinline__ unsigned short f32_to_bf16_rne(float f) {
    unsigned u = __float_as_uint(f);
    u = u + 0x7FFFu + ((u >> 16) & 1u);   // round-to-nearest-even
    return (unsigned short)(u >> 16);
}

// ---------------------------------------------------------------------------
// Init: cast W->bf16 (tier A2), transpose W (fallback tiers), zero deg.
// Disjoint thread ranges; null pointers skip a section.
// ---------------------------------------------------------------------------
__global__ void gcn_init(const float* __restrict__ W, float* __restrict__ Wt,
                         unsigned short* __restrict__ Wb,
                         int* __restrict__ deg, int n_nodes) {
    int t = blockIdx.x * blockDim.x + threadIdx.x;
    if (t < N_FEATS * N_FEATS / 8) {             // W: 8 floats -> 8 bf16
        if (Wb) {
            const float4* f4 = reinterpret_cast<const float4*>(W) + (size_t)t * 2;
            float4 x0 = f4[0];
            float4 x1 = f4[1];
            ushort4 o0, o1;
            o0.x = f32_to_bf16_rne(x0.x); o0.y = f32_to_bf16_rne(x0.y);
            o0.z = f32_to_bf16_rne(x0.z); o0.w = f32_to_bf16_rne(x0.w);
            o1.x = f32_to_bf16_rne(x1.x); o1.y = f32_to_bf16_rne(x1.y);
            o1.z = f32_to_bf16_rne(x1.z); o1.w = f32_to_bf16_rne(x1.w);
            reinterpret_cast<ushort4*>(Wb)[(size_t)t * 2 + 0] = o0;
            reinterpret_cast<ushort4*>(Wb)[(size_t)t * 2 + 1] = o1;
        }
        return;
    }
    int t2 = t - N_FEATS * N_FEATS / 8;
    if (t2 < N_FEATS * N_FEATS) {                // transpose W (fp32 fallback GEMM)
        if (Wt) {
            int o = t2 >> 7;
            int i = t2 & 127;
            Wt[i * N_FEATS + o] = W[o * N_FEATS + i];
        }
        return;
    }
    int u = t2 - N_FEATS * N_FEATS;
    if (u < n_nodes) deg[u] = 0;                 // zero deg
}

// ---------------------------------------------------------------------------
// Transform (tier A2): Y[m][o] = bf16( sum_k feature[m][k] * W[o][k] )
// One wave per 16-row stripe; A = feature fp32 cast inline; B = Wb rows.
// mfma_f32_16x16x32_bf16: A lane row=l&15, k-chunk=l>>4; B lane col=l&15,
// k-chunk=l>>4; C/D col=l&15, row=(l>>4)*4+reg (m89-verified mapping).
// ---------------------------------------------------------------------------
__launch_bounds__(256)
__global__ void gcn_transform_mfma(const float* __restrict__ feat,
                                   const unsigned short* __restrict__ Wb,
                                   unsigned short* __restrict__ Y,
                                   int n_nodes) {
    const long long gtid = (long long)blockIdx.x * blockDim.x + threadIdx.x;
    const int wave = (int)(gtid >> 6);
    const int row0 = wave * 16;
    if (row0 >= n_nodes) return;
    const int l = (int)(threadIdx.x & 63);
    const int lr = l & 15;        // A row within stripe / B,D column
    const int kb = l >> 4;        // k-block 0..3 (8 k each)

    // ---- A frags: row row0+lr, inline fp32 -> bf16 cast ----
    bf16x8 afrag[4] = {};
    if (row0 + lr < n_nodes) {
        const float* aptr = feat + (size_t)(row0 + lr) * N_FEATS + kb * 8;
#pragma unroll
        for (int kk = 0; kk < 4; ++kk) {
            float4 x0 = *reinterpret_cast<const float4*>(aptr + kk * 32);
            float4 x1 = *reinterpret_cast<const float4*>(aptr + kk * 32 + 4);
            bf16x8 af;
            af[0] = (short)f32_to_bf16_rne(x0.x);
            af[1] = (short)f32_to_bf16_rne(x0.y);
            af[2] = (short)f32_to_bf16_rne(x0.z);
            af[3] = (short)f32_to_bf16_rne(x0.w);
            af[4] = (short)f32_to_bf16_rne(x1.x);
            af[5] = (short)f32_to_bf16_rne(x1.y);
            af[6] = (short)f32_to_bf16_rne(x1.z);
            af[7] = (short)f32_to_bf16_rne(x1.w);
            afrag[kk] = af;
        }
    }

    f32x4 acc[8];
#pragma unroll
    for (int nt = 0; nt < 8; ++nt) acc[nt] = (f32x4){0.f, 0.f, 0.f, 0.f};

#pragma unroll
    for (int nt = 0; nt < 8; ++nt) {
        const unsigned short* wp = Wb + (size_t)(nt * 16 + lr) * N_FEATS + kb * 8;
#pragma unroll
        for (int kk = 0; kk < 4; ++kk) {
            bf16x8 bfrag = *reinterpret_cast<const bf16x8*>(wp + kk * 32);
            acc[nt] = __builtin_amdgcn_mfma_f32_16x16x32_bf16(afrag[kk], bfrag, acc[nt], 0, 0, 0);
        }
    }

    // ---- epilogue: store Y bf16 ----
#pragma unroll
    for (int nt = 0; nt < 8; ++nt) {
        const int col = nt * 16 + lr;
#pragma unroll
        for (int j = 0; j < 4; ++j) {
            const int r = row0 + kb * 4 + j;
            if (r < n_nodes)
                Y[(size_t)r * N_FEATS + col] = f32_to_bf16_rne(acc[nt][j]);
        }
    }
}

// ---------------------------------------------------------------------------
// CSR pass 1: histogram AND per-edge slot position (guards both indices).
// ---------------------------------------------------------------------------
__global__ void gcn_hist_pos(const int* __restrict__ src, const int* __restrict__ dst,
                             int* __restrict__ deg, int* __restrict__ pos,
                             int n_edges, int n_nodes) {
    int e = blockIdx.x * blockDim.x + threadIdx.x;
    if (e >= n_edges) return;
    int d = dst[e];
    int s = src[e];
    if ((unsigned)d < (unsigned)n_nodes && (unsigned)s < (unsigned)n_nodes)
        pos[e] = atomicAdd(&deg[d], 1);
}

// Tier B histogram (no pos array)
__global__ void gcn_hist(const int* __restrict__ src, const int* __restrict__ dst,
                         int* __restrict__ deg, int n_edges, int n_nodes) {
    int e = blockIdx.x * blockDim.x + threadIdx.x;
    if (e >= n_edges) return;
    int d = dst[e];
    int s = src[e];
    if ((unsigned)d < (unsigned)n_nodes && (unsigned)s < (unsigned)n_nodes)
        atomicAdd(&deg[d], 1);
}

// ---------------------------------------------------------------------------
// Scan phase 1: per-chunk sums.
// ---------------------------------------------------------------------------
__launch_bounds__(256)
__global__ void gcn_scan_part(const int* __restrict__ deg, int* __restrict__ chunk_sum, int n) {
    const int t = threadIdx.x;
    const int base = blockIdx.x * SCAN_CHUNK;
    int sum = 0;
#pragma unroll
    for (int k = 0; k < 4; ++k) {
        int idx = base + k * 256 + t;
        if (idx < n) sum += deg[idx];
    }
    for (int d = 1; d < 64; d <<= 1) sum += __shfl_xor(sum, d, 64);
    __shared__ int wsum[4];
    if ((t & 63) == 0) wsum[t >> 6] = sum;
    __syncthreads();
    if (t == 0) chunk_sum[blockIdx.x] = wsum[0] + wsum[1] + wsum[2] + wsum[3];
}

// ---------------------------------------------------------------------------
// Scan phase 2: inline chunk offset + per-chunk exclusive scan.
// Optionally zeroes cursor (tier B). Last block writes row_start[n].
// ---------------------------------------------------------------------------
__launch_bounds__(256)
__global__ void gcn_scan_final(const int* __restrict__ deg, const int* __restrict__ chunk_sum,
                               int* __restrict__ row_start, int* __restrict__ cursor,
                               int n, int nchunks) {
    const int t = threadIdx.x;
    const int b = blockIdx.x;

    int v = 0;
    for (int j = t; j < b; j += 256) v += chunk_sum[j];
    for (int d = 1; d < 64; d <<= 1) v += __shfl_xor(v, d, 64);
    __shared__ int owsum[4];
    __shared__ int s_off;
    if ((t & 63) == 0) owsum[t >> 6] = v;
    __syncthreads();
    if (t == 0) s_off = owsum[0] + owsum[1] + owsum[2] + owsum[3];
    __syncthreads();
    const int chunk_off = s_off;

    const int base = b * SCAN_CHUNK;
    const int idx0 = base + t * 4;
    int x[4];
#pragma unroll
    for (int k = 0; k < 4; ++k) {
        int idx = idx0 + k;
        x[k] = (idx < n) ? deg[idx] : 0;
    }
    const int tsum = x[0] + x[1] + x[2] + x[3];

    const int lane = t & 63, w = t >> 6;
    int inc = tsum;
    for (int d = 1; d < 64; d <<= 1) {
        int sv = __shfl_up(inc, d, 64);
        if (lane >= d) inc += sv;
    }
    __shared__ int wsum[4];
    if (lane == 63) wsum[w] = inc;
    __syncthreads();
    int woff = 0;
    for (int i = 0; i < w; ++i) woff += wsum[i];

    int run = chunk_off + woff + inc - tsum;
#pragma unroll
    for (int k = 0; k < 4; ++k) {
        int idx = idx0 + k;
        if (idx < n) {
            row_start[idx] = run;
            if (cursor) cursor[idx] = 0;
        }
        run += x[k];
    }

    if (t == 0 && b == nchunks - 1)
        row_start[n] = chunk_off + wsum[0] + wsum[1] + wsum[2] + wsum[3];
}

// ---------------------------------------------------------------------------
// CSR scatter, atomic-free (uses precomputed pos).
// ---------------------------------------------------------------------------
__global__ void gcn_build_csr_pos(const int* __restrict__ src, const int* __restrict__ dst,
                                  const int* __restrict__ row_start, const int* __restrict__ pos,
                                  int* __restrict__ csr_src, int n_edges, int n_nodes) {
    int e = blockIdx.x * blockDim.x + threadIdx.x;
    if (e >= n_edges) return;
    int d = dst[e];
    int s = src[e];
    if ((unsigned)d >= (unsigned)n_nodes || (unsigned)s >= (unsigned)n_nodes) return;
    csr_src[row_start[d] + pos[e]] = s;
}

// CSR scatter, atomic cursor (tier B).
__global__ void gcn_build_csr(const int* __restrict__ src, const int* __restrict__ dst,
                              const int* __restrict__ row_start, int* __restrict__ cursor,
                              int* __restrict__ csr_src, int n_edges, int n_nodes) {
    int e = blockIdx.x * blockDim.x + threadIdx.x;
    if (e >= n_edges) return;
    int d = dst[e];
    int s = src[e];
    if ((unsigned)d >= (unsigned)n_nodes || (unsigned)s >= (unsigned)n_nodes) return;
    int p = atomicAdd(&cursor[d], 1);
    csr_src[row_start[d] + p] = s;
}

// ---------------------------------------------------------------------------
// bf16 aggregation + bias (tier A2): one wave per node, quarter-wave per
// edge-row (16 lanes x 16B = 256B), 16 edges in flight, fp32 accumulate,
// cross-quarter shfl combine, + bias, write fp32 out.
// ---------------------------------------------------------------------------
#define BACC(acc, v)                                              \
    do {                                                          \
        unsigned uu;                                              \
        uu = (v).x;                                               \
        acc[0] += __uint_as_float(uu << 16);                      \
        acc[1] += __uint_as_float(uu & 0xFFFF0000u);              \
        uu = (v).y;                                               \
        acc[2] += __uint_as_float(uu << 16);                      \
        acc[3] += __uint_as_float(uu & 0xFFFF0000u);              \
        uu = (v).z;                                               \
        acc[4] += __uint_as_float(uu << 16);                      \
        acc[5] += __uint_as_float(uu & 0xFFFF0000u);              \
        uu = (v).w;                                               \
        acc[6] += __uint_as_float(uu << 16);                      \
        acc[7] += __uint_as_float(uu & 0xFFFF0000u);              \
    } while (0)

__launch_bounds__(256)
__global__ void gcn_aggregate_bf16(const uint4* __restrict__ Y,
                                   const int* __restrict__ row_start,
                                   const int* __restrict__ csr_src,
                                   const float* __restrict__ bias,
                                   float* __restrict__ out, int n_nodes) {
    int node = blockIdx.x * 4 + (threadIdx.x >> 6);
    if (node >= n_nodes) return;
    const int l = threadIdx.x & 63;
    const int qw = l >> 4;       // quarter-wave 0..3 (edge slot)
    const int ql = l & 15;       // 16B chunk within the 256B row
    int beg = row_start[node];
    int end = row_start[node + 1];

    float a0[8] = {0,0,0,0,0,0,0,0};
    float a1[8] = {0,0,0,0,0,0,0,0};
    float a2[8] = {0,0,0,0,0,0,0,0};
    float a3[8] = {0,0,0,0,0,0,0,0};

    int i = beg;
    for (; i + 16 <= end; i += 16) {             // 16 edges per iter
        int s0 = csr_src[i + qw];
        int s1 = csr_src[i + 4 + qw];
        int s2 = csr_src[i + 8 + qw];
        int s3 = csr_src[i + 12 + qw];
        uint4 v0 = Y[(size_t)s0 * 16 + ql];
        uint4 v1 = Y[(size_t)s1 * 16 + ql];
        uint4 v2 = Y[(size_t)s2 * 16 + ql];
        uint4 v3 = Y[(size_t)s3 * 16 + ql];
        BACC(a0, v0);
        BACC(a1, v1);
        BACC(a2, v2);
        BACC(a3, v3);
    }
    for (; i + 4 <= end; i += 4) {               // groups of 4 (<=3 iters)
        int s = csr_src[i + qw];
        uint4 v = Y[(size_t)s * 16 + ql];
        BACC(a0, v);
    }
    int rem = end - i;                           // <4 leftover edges
    if (qw < rem) {
        int s = csr_src[i + qw];
        uint4 v = Y[(size_t)s * 16 + ql];
        BACC(a0, v);
    }

    float r[8];
#pragma unroll
    for (int k = 0; k < 8; ++k) {
        r[k] = a0[k] + a1[k] + a2[k] + a3[k];
        r[k] += __shfl_xor(r[k], 16, 64);
        r[k] += __shfl_xor(r[k], 32, 64);
    }

    if (qw == 0) {                               // lanes 0..15 write the row
        const float4 b0 = *reinterpret_cast<const float4*>(bias + ql * 8);
        const float4 b1 = *reinterpret_cast<const float4*>(bias + ql * 8 + 4);
        float4* o4 = reinterpret_cast<float4*>(out + (size_t)node * N_FEATS + ql * 8);
        o4[0] = make_float4(r[0] + b0.x, r[1] + b0.y, r[2] + b0.z, r[3] + b0.w);
        o4[1] = make_float4(r[4] + b1.x, r[5] + b1.y, r[6] + b1.z, r[7] + b1.w);
    }
}

// ---------------------------------------------------------------------------
// fp32 aggregation (tier A/B fallback): half-wave float4, 8 edges in flight.
// ---------------------------------------------------------------------------
__launch_bounds__(256)
__global__ void gcn_aggregate(const float* __restrict__ feat,
                              const int* __restrict__ row_start,
                              const int* __restrict__ csr_src,
                              float* __restrict__ out, int n_nodes) {
    int node = blockIdx.x * 4 + (threadIdx.x >> 6);
    if (node >= n_nodes) return;
    const int l = threadIdx.x & 63;
    const int q = l & 31;
    const int h = l >> 5;
    int beg = row_start[node];
    int end = row_start[node + 1];
    const float4* f4 = reinterpret_cast<const float4*>(feat);

    float4 a0 = make_float4(0.f, 0.f, 0.f, 0.f);
    float4 a1 = a0, a2 = a0, a3 = a0;
    int i = beg;
    for (; i + 8 <= end; i += 8) {
        int s0 = csr_src[i + h];
        int s1 = csr_src[i + 2 + h];
        int s2 = csr_src[i + 4 + h];
        int s3 = csr_src[i + 6 + h];
        float4 v0 = f4[(size_t)s0 * 32 + q];
        float4 v1 = f4[(size_t)s1 * 32 + q];
        float4 v2 = f4[(size_t)s2 * 32 + q];
        float4 v3 = f4[(size_t)s3 * 32 + q];
        a0.x += v0.x; a0.y += v0.y; a0.z += v0.z; a0.w += v0.w;
        a1.x += v1.x; a1.y += v1.y; a1.z += v1.z; a1.w += v1.w;
        a2.x += v2.x; a2.y += v2.y; a2.z += v2.z; a2.w += v2.w;
        a3.x += v3.x; a3.y += v3.y; a3.z += v3.z; a3.w += v3.w;
    }
    for (; i + 2 <= end; i += 2) {
        int s0 = csr_src[i + h];
        float4 v0 = f4[(size_t)s0 * 32 + q];
        a0.x += v0.x; a0.y += v0.y; a0.z += v0.z; a0.w += v0.w;
    }
    if (i < end && h == 0) {
        int s = csr_src[i];
        float4 v = f4[(size_t)s * 32 + q];
        a0.x += v.x; a0.y += v.y; a0.z += v.z; a0.w += v.w;
    }

    float4 acc = make_float4(a0.x + a1.x + a2.x + a3.x,
                             a0.y + a1.y + a2.y + a3.y,
                             a0.z + a1.z + a2.z + a3.z,
                             a0.w + a1.w + a2.w + a3.w);
    acc.x += __shfl_xor(acc.x, 32, 64);
    acc.y += __shfl_xor(acc.y, 32, 64);
    acc.z += __shfl_xor(acc.z, 32, 64);
    acc.w += __shfl_xor(acc.w, 32, 64);

    if (h == 0)
        reinterpret_cast<float4*>(out)[(size_t)node * 32 + q] = acc;
}

// ---------------------------------------------------------------------------
// Fallback scatter-add (tier C).
// ---------------------------------------------------------------------------
__global__ void gcn_scatter_add(const float* __restrict__ feat,
                                const int* __restrict__ src,
                                const int* __restrict__ dst,
                                float* __restrict__ agg,
                                int n_edges, int n_nodes) {
    long long tid = (long long)blockIdx.x * blockDim.x + threadIdx.x;
    int e = (int)(tid >> 5);
    if (e >= n_edges) return;
    int j = (int)(tid & 31);
    int s = src[e];
    int d = dst[e];
    if ((unsigned)s >= (unsigned)n_nodes || (unsigned)d >= (unsigned)n_nodes) return;
    const float4 v = *reinterpret_cast<const float4*>(feat + (size_t)s * N_FEATS + j * 4);
    float* p = agg + (size_t)d * N_FEATS + j * 4;
    atomicAdd(p + 0, v.x);
    atomicAdd(p + 1, v.y);
    atomicAdd(p + 2, v.z);
    atomicAdd(p + 3, v.w);
}

// ---------------------------------------------------------------------------
// fp32 VALU GEMM (fallback tiers), in place on d_out.
// ---------------------------------------------------------------------------
__launch_bounds__(256)
__global__ void gcn_gemm_inplace(float* __restrict__ out,
                                 const float* __restrict__ Wt,
                                 const float* __restrict__ b,
                                 int n_nodes) {
    __shared__ float a_lds[32 * N_FEATS];   // 16 KB

    const int t = threadIdx.x;
    const int node0 = blockIdx.x * 32;
    const int rows = min(32, n_nodes - node0);

    float4* a4 = reinterpret_cast<float4*>(a_lds);
    const float4* out4 = reinterpret_cast<const float4*>(out + (size_t)node0 * N_FEATS);
    const int nflt4 = rows * (N_FEATS / 4);
    for (int idx = t; idx < nflt4; idx += 256) a4[idx] = out4[idx];
    __syncthreads();

    const int oq = t & 31;
    const int ng = t >> 5;

    const float4 bb = reinterpret_cast<const float4*>(b)[oq];
    float4 acc[4];
#pragma unroll
    for (int k = 0; k < 4; ++k) acc[k] = bb;

    const float4* Wt4 = reinterpret_cast<const float4*>(Wt);
#pragma unroll 4
    for (int i = 0; i < N_FEATS; ++i) {
        const float4 w = Wt4[i * 32 + oq];
#pragma unroll
        for (int k = 0; k < 4; ++k) {
            const float a = a_lds[(ng * 4 + k) * N_FEATS + i];
            acc[k].x += a * w.x;
            acc[k].y += a * w.y;
            acc[k].z += a * w.z;
            acc[k].w += a * w.w;
        }
    }

    __syncthreads();

#pragma unroll
    for (int k = 0; k < 4; ++k) {
        const int r = ng * 4 + k;
        if (r < rows) {
            reinterpret_cast<float4*>(out + (size_t)(node0 + r) * N_FEATS)[oq] = acc[k];
        }
    }
}

extern "C" void kernel_launch(void* const* d_in, const int* in_sizes, int n_in,
                              void* d_out, int out_size, void* d_ws, size_t ws_size,
                              hipStream_t stream) {
    const float* feature = (const float*)d_in[0];
    const int*   src     = (const int*)d_in[1];
    const int*   dst     = (const int*)d_in[2];
    const float* W       = (const float*)d_in[3];
    const float* b       = (const float*)d_in[4];
    float* out = (float*)d_out;

    const int n_nodes = in_sizes[0] / N_FEATS;
    const int n_edges = in_sizes[1];
    const int nchunks = (n_nodes + SCAN_CHUNK - 1) / SCAN_CHUNK;

    // ---- workspace layout (256 B aligned) ----
    char* ws = (char*)d_ws;
    size_t off = 0;
    auto take = [&](size_t bytes) -> char* {
        char* p = ws + off;
        off = (off + bytes + 255) & ~(size_t)255;
        return p;
    };
    // common
    float* Wt        = (float*)take((size_t)N_FEATS * N_FEATS * sizeof(float));
    int*   deg       = (int*)  take((size_t)n_nodes * sizeof(int));
    int*   row_start = (int*)  take(((size_t)n_nodes + 1) * sizeof(int));
    int*   chunk_sum = (int*)  take((size_t)nchunks * sizeof(int));
    int*   csr_src   = (int*)  take((size_t)n_edges * sizeof(int));
    const size_t off_common = off;

    // tier A2: bf16 Y (transformed features) + bf16 W + pos
    unsigned short* Yb = (unsigned short*)take((size_t)n_nodes * N_FEATS * sizeof(unsigned short));
    unsigned short* Wb = (unsigned short*)take((size_t)N_FEATS * N_FEATS * sizeof(unsigned short));
    int* posA2 = (int*)take((size_t)n_edges * sizeof(int));
    const bool tierA2 = (off <= ws_size);
    // tier A: pos only
    off = off_common;
    int* posA = (int*)take((size_t)n_edges * sizeof(int));
    const bool tierA = !tierA2 && (off <= ws_size);
    // tier B: cursor only
    off = off_common;
    int* cursor = (int*)take((size_t)n_nodes * sizeof(int));
    const bool tierB = !tierA2 && !tierA && (off <= ws_size);

    const int init_elems = N_FEATS * N_FEATS / 8 + N_FEATS * N_FEATS + n_nodes;

    if (tierA2 || tierA || tierB) {
        gcn_init<<<(init_elems + 255) / 256, 256, 0, stream>>>(
            W, tierA2 ? (float*)nullptr : Wt,
            tierA2 ? Wb : (unsigned short*)nullptr, deg, n_nodes);

        if (tierA2) {
            const long long nthr = (long long)((n_nodes + 15) / 16) * 64;
            gcn_transform_mfma<<<(int)((nthr + 255) / 256), 256, 0, stream>>>(
                feature, Wb, Yb, n_nodes);
        }

        const int eblocks = (n_edges + 255) / 256;
        int* pos = tierA2 ? posA2 : posA;
        if (tierA2 || tierA) {
            gcn_hist_pos<<<eblocks, 256, 0, stream>>>(src, dst, deg, pos, n_edges, n_nodes);
        } else {
            gcn_hist<<<eblocks, 256, 0, stream>>>(src, dst, deg, n_edges, n_nodes);
        }
        gcn_scan_part<<<nchunks, 256, 0, stream>>>(deg, chunk_sum, n_nodes);
        gcn_scan_final<<<nchunks, 256, 0, stream>>>(deg, chunk_sum, row_start,
                                                    (tierA2 || tierA) ? (int*)nullptr : cursor,
                                                    n_nodes, nchunks);
        if (tierA2 || tierA) {
            gcn_build_csr_pos<<<eblocks, 256, 0, stream>>>(
                src, dst, row_start, pos, csr_src, n_edges, n_nodes);
        } else {
            gcn_build_csr<<<eblocks, 256, 0, stream>>>(
                src, dst, row_start, cursor, csr_src, n_edges, n_nodes);
        }
        if (tierA2) {
            // aggregate transformed features + bias -> done, no trailing GEMM
            gcn_aggregate_bf16<<<(n_nodes + 3) / 4, 256, 0, stream>>>(
                reinterpret_cast<const uint4*>(Yb), row_start, csr_src, b, out, n_nodes);
        } else {
            gcn_aggregate<<<(n_nodes + 3) / 4, 256, 0, stream>>>(
                feature, row_start, csr_src, out, n_nodes);
            gcn_gemm_inplace<<<(n_nodes + 31) / 32, 256, 0, stream>>>(out, Wt, b, n_nodes);
        }
    } else {
        // tier C: atomic scatter + fp32 GEMM
        gcn_init<<<(init_elems + 255) / 256, 256, 0, stream>>>(
            W, Wt, (unsigned short*)nullptr, deg, n_nodes);
        hipMemsetAsync(d_out, 0, (size_t)n_nodes * N_FEATS * sizeof(float), stream);
        long long total = (long long)n_edges * 32;
        gcn_scatter_add<<<(int)((total + 255) / 256), 256, 0, stream>>>(
            feature, src, dst, out, n_edges, n_nodes);
        gcn_gemm_inplace<<<(n_nodes + 31) / 32, 256, 0, stream>>>(out, Wt, b, n_nodes);
    }
}